// Round 1
// 359.905 us; speedup vs baseline: 1.0270x; 1.0270x over previous
//
#include <hip/hip_runtime.h>
#include <hip/hip_bf16.h>
#include <math.h>

#define B_ 4
#define N_ 6
#define FD_ 256
#define D_ 128
#define HF_ 64
#define WF_ 120
#define P_ (HF_*WF_)   // 7680

typedef __attribute__((ext_vector_type(8))) short short8;
typedef __attribute__((ext_vector_type(4))) float floatx4;
typedef __attribute__((ext_vector_type(4))) unsigned int uint4e;

__device__ inline float gred_sum(float v) {   // sum within 16-lane group
  v += __shfl_xor(v, 1); v += __shfl_xor(v, 2);
  v += __shfl_xor(v, 4); v += __shfl_xor(v, 8);
  return v;
}

__device__ inline float gred32(float v) {     // sum within 32-lane group
  v += __shfl_xor(v, 1); v += __shfl_xor(v, 2);
  v += __shfl_xor(v, 4); v += __shfl_xor(v, 8);
  v += __shfl_xor(v, 16);
  return v;
}

__device__ inline unsigned short f2bf(float f) {
  unsigned int u = __builtin_bit_cast(unsigned int, f);
  u += 0x7fffu + ((u >> 16) & 1u);   // RNE
  return (unsigned short)(u >> 16);
}
__device__ inline float bf2f(unsigned short h) {
  return __builtin_bit_cast(float, ((unsigned int)h) << 16);
}
__device__ inline void bfu2(unsigned int u, float& lo, float& hi) {
  lo = __builtin_bit_cast(float, u << 16);
  hi = __builtin_bit_cast(float, u & 0xffff0000u);
}

// ---------------------------------------------------------------------------
// prep: BN fold + homographies
// ---------------------------------------------------------------------------
__global__ void prep_kernel(const float* __restrict__ I_src, const float* __restrict__ I_tar_inv,
                            const float* __restrict__ E, const float* __restrict__ dis,
                            const float* __restrict__ norm_vec,
                            const float* __restrict__ bn_gamma, const float* __restrict__ bn_beta,
                            const float* __restrict__ bn_mean, const float* __restrict__ bn_var,
                            float* __restrict__ bnscale, float* __restrict__ bnbias,
                            float* __restrict__ Hm) {
  int t = threadIdx.x;
  if (t < FD_) {
    float s = bn_gamma[t] * rsqrtf(bn_var[t] + 1e-5f);
    bnscale[t] = s;
    bnbias[t] = bn_beta[t] - bn_mean[t] * s;
  }
  if (t < B_*N_) {
    int b = t / N_;
    const float* e = E + t*16;
    const float* nv = norm_vec + b*3;
    float inv_dis = 1.0f / dis[0];
    float M[9];
    #pragma unroll
    for (int r = 0; r < 3; r++)
      #pragma unroll
      for (int c = 0; c < 3; c++)
        M[r*3+c] = e[r*4+c] - e[r*4+3]*nv[c]*inv_dis;
    const float* Is = I_src + t*9;
    float A[9];
    #pragma unroll
    for (int r = 0; r < 3; r++)
      #pragma unroll
      for (int c = 0; c < 3; c++)
        A[r*3+c] = Is[r*3+0]*M[0*3+c] + Is[r*3+1]*M[1*3+c] + Is[r*3+2]*M[2*3+c];
    const float* It = I_tar_inv + b*9;
    #pragma unroll
    for (int r = 0; r < 3; r++)
      #pragma unroll
      for (int c = 0; c < 3; c++)
        Hm[t*9 + r*3+c] = A[r*3+0]*It[0*3+c] + A[r*3+1]*It[1*3+c] + A[r*3+2]*It[2*3+c];
  }
}

// ---------------------------------------------------------------------------
// uv precompute: sx,sy per (b,n,p). 184320 = 720*256 exactly.
// ---------------------------------------------------------------------------
__global__ void uv_kernel(const float* __restrict__ Hm, float2* __restrict__ uvbuf) {
  int t = blockIdx.x * 256 + threadIdx.x;
  int p  = t % P_;
  int bn = t / P_;
  int py = p / WF_, px = p - py*WF_;
  float pixx = (float)px * (960.f/119.f);
  float pixy = (float)py * (480.f/63.f);
  const float* H = Hm + bn*9;
  float hx = H[0]*pixx + H[1]*pixy + H[2];
  float hy = H[3]*pixx + H[4]*pixy + H[5];
  float hz = H[6]*pixx + H[7]*pixy + H[8];
  float sx = (hx/hz) * ((float)WF_/960.f);
  float sy = (hy/hz) * ((float)HF_/480.f);
  uvbuf[t] = make_float2(sx, sy);
}

// ---------------------------------------------------------------------------
// swizzle conv_w (D,FD) fp32 -> bf16 B-fragment order
// ---------------------------------------------------------------------------
__global__ void swizzle_w_kernel(const float* __restrict__ conv_w, unsigned short* __restrict__ wswz) {
  int t = blockIdx.x * 256 + threadIdx.x;   // 0..32767
  int j    =  t        & 7;
  int lane = (t >> 3)  & 63;
  int dt   = (t >> 9)  & 7;
  int kc   =  t >> 12;
  int d = dt*16 + (lane & 15);
  int k = kc*32 + (lane >> 4)*8 + j;
  wswz[t] = f2bf(conv_w[d*FD_ + k]);
}

// ---------------------------------------------------------------------------
// swizzle mlp weights to B-frag order bf16
// ---------------------------------------------------------------------------
__global__ void swizzle_mlp_kernel(const float* __restrict__ w1, const float* __restrict__ w2,
                                   unsigned short* __restrict__ w1s, unsigned short* __restrict__ w2s) {
  int t = blockIdx.x * 256 + threadIdx.x;   // 0..65535
  if (t < 32768) {
    int j    =  t        & 7;
    int lane = (t >> 3)  & 63;
    int dt   = (t >> 9)  & 15;
    int kc   =  t >> 13;
    int n = dt*16 + (lane & 15);
    int k = kc*32 + (lane >> 4)*8 + j;
    w1s[t] = f2bf(w1[k*256 + n]);
  } else {
    int u = t - 32768;
    int j    =  u        & 7;
    int lane = (u >> 3)  & 63;
    int dt   = (u >> 9)  & 7;
    int kc   =  u >> 12;
    int n = dt*16 + (lane & 15);
    int k = kc*32 + (lane >> 4)*8 + j;
    w2s[u] = f2bf(w2[k*128 + n]);
  }
}

// ---------------------------------------------------------------------------
// conv (MFMA): depth-2 register prefetch (loads live across the barrier),
// LDS double-buffer, ytile aliases apad (19.4 KB LDS -> 8 blocks/CU).
// block: 64 p x 128 d, 4 waves.
// ---------------------------------------------------------------------------
#define AST_ 36   // apad stride in shorts (72 B rows, 8B-aligned frag reads)
__global__ __launch_bounds__(256) void conv_kernel(const float* __restrict__ feature,
    const unsigned short* __restrict__ wswz, const float* __restrict__ bnscale,
    const float* __restrict__ bnbias, unsigned short* __restrict__ val) {
  __shared__ __align__(16) char csm[19968];
  unsigned short* apadA = (unsigned short*)csm;            // 64*36*2 = 4608 B
  unsigned short* apadB = (unsigned short*)(csm + 4608);   // 4608 B
  unsigned short* ytile = (unsigned short*)csm;            // 64*136*2 = 17408 B (alias)
  float* sbn = (float*)(csm + 17408);                      // 2048 B

  int tid = threadIdx.x;
  sbn[tid] = bnscale[tid]; sbn[256+tid] = bnbias[tid];

  int bn = blockIdx.y;
  int p0 = blockIdx.x * 64;
  const float* fbase2 = feature + (size_t)bn*FD_*P_ + p0;

  int K0 = tid >> 4;   // k-pair index within chunk
  int sp = (tid & 15) * 4;

  int ln = tid & 63, wv = tid >> 6;
  int m = ln & 15, q = ln >> 4;
  int row = wv*16 + m;

  float4 va[2], vb[2];
  // prolog loads: chunks 0,1
  {
    const float* fb0 = fbase2 + (size_t)(2*K0)*P_ + sp;
    va[0] = *(const float4*)fb0; vb[0] = *(const float4*)(fb0 + P_);
    const float* fb1 = fbase2 + (size_t)(32 + 2*K0)*P_ + sp;
    va[1] = *(const float4*)fb1; vb[1] = *(const float4*)(fb1 + P_);
  }
  __syncthreads();   // sbn visible

  floatx4 acc[8];
  #pragma unroll
  for (int dt = 0; dt < 8; dt++) acc[dt] = (floatx4){0.f,0.f,0.f,0.f};

  // pack chunk0 -> apadA
  {
    int k0 = 0;
    float s0 = sbn[k0+2*K0],   b0 = sbn[256+k0+2*K0];
    float s1 = sbn[k0+2*K0+1], b1 = sbn[256+k0+2*K0+1];
    float a0[4] = {va[0].x, va[0].y, va[0].z, va[0].w};
    float a1[4] = {vb[0].x, vb[0].y, vb[0].z, vb[0].w};
    #pragma unroll
    for (int i = 0; i < 4; i++) {
      unsigned int w = (unsigned int)f2bf(fmaxf(a0[i]*s0+b0, 0.f))
                     | ((unsigned int)f2bf(fmaxf(a1[i]*s1+b1, 0.f)) << 16);
      *(unsigned int*)&apadA[(sp+i)*AST_ + 2*K0] = w;
    }
  }

  #pragma unroll
  for (int kc = 0; kc < 8; kc++) {
    __syncthreads();
    // issue loads for chunk kc+2 (stay in flight across this whole iteration)
    if (kc + 2 < 8) {
      const float* fb = fbase2 + (size_t)((kc+2)*32 + 2*K0)*P_ + sp;
      va[kc&1] = *(const float4*)fb;
      vb[kc&1] = *(const float4*)(fb + P_);
    }
    // pack+write chunk kc+1 (its loads were issued a full iteration ago)
    if (kc + 1 < 8) {
      int s = (kc+1)&1;
      int k0 = (kc+1)*32;
      unsigned short* ap = ((kc+1)&1) ? apadB : apadA;
      float s0 = sbn[k0+2*K0],   b0 = sbn[256+k0+2*K0];
      float s1 = sbn[k0+2*K0+1], b1 = sbn[256+k0+2*K0+1];
      float a0[4] = {va[s].x, va[s].y, va[s].z, va[s].w};
      float a1[4] = {vb[s].x, vb[s].y, vb[s].z, vb[s].w};
      #pragma unroll
      for (int i = 0; i < 4; i++) {
        unsigned int w = (unsigned int)f2bf(fmaxf(a0[i]*s0+b0, 0.f))
                       | ((unsigned int)f2bf(fmaxf(a1[i]*s1+b1, 0.f)) << 16);
        *(unsigned int*)&ap[(sp+i)*AST_ + 2*K0] = w;
      }
    }
    // MFMA chunk kc
    unsigned short* rp = (kc&1) ? apadB : apadA;
    uint2 u0 = *(const uint2*)&rp[row*AST_ + q*8];
    uint2 u1 = *(const uint2*)&rp[row*AST_ + q*8 + 4];
    uint4e ua = {u0.x, u0.y, u1.x, u1.y};
    short8 af = __builtin_bit_cast(short8, ua);
    #pragma unroll
    for (int dt = 0; dt < 8; dt++) {
      short8 bfg = *(const short8*)(wswz + (((size_t)kc*8 + dt)*64 + ln)*8);
      acc[dt] = __builtin_amdgcn_mfma_f32_16x16x32_bf16(af, bfg, acc[dt], 0, 0, 0);
    }
  }
  __syncthreads();   // all apad reads done before ytile alias writes

  #pragma unroll
  for (int dt = 0; dt < 8; dt++)
    #pragma unroll
    for (int r = 0; r < 4; r++)
      ytile[(wv*16 + q*4 + r)*136 + dt*16 + m] = f2bf(acc[dt][r]);
  __syncthreads();
  #pragma unroll
  for (int i = 0; i < 4; i++) {
    int idx = tid + i*256;
    int pp = idx >> 4, ch = idx & 15;
    uint4 v = *(const uint4*)&ytile[pp*136 + ch*8];
    *(uint4*)(val + ((size_t)bn*P_ + p0 + pp)*D_ + ch*8) = v;
  }
}

// ---------------------------------------------------------------------------
// att v2: 32-lane group per point (4 ch/lane) -> per-thread state halved
// (target ~100 VGPR, 4-5 waves/SIMD vs ~3 before), 1 point per thread,
// 8 points/block, grid 960x4 (4x more blocks to schedule), gathers issued
// in n-pairs ahead of math for memory-level parallelism, XCD-chunked
// blockIdx.x swizzle so each XCD's L2 holds a contiguous ~2MB val slice.
// ---------------------------------------------------------------------------
__global__ __launch_bounds__(256, 4) void att_kernel(const unsigned short* __restrict__ val,
    const float2* __restrict__ uvbuf, const float* __restrict__ ln1_g,
    const float* __restrict__ ln1_b, unsigned short* __restrict__ zbuf) {
  int b = blockIdx.y;
  int bx = blockIdx.x;
  int tile = (bx & 7) * 120 + (bx >> 3);   // 960 tiles, 960%8==0 -> bijective
  int p0 = tile * 8;
  int tid = threadIdx.x;
  int ln = tid & 63, wv = tid >> 6;
  int grp = ln >> 5, c = ln & 31;          // 2 points per wave, 32 lanes each
  int p = p0 + wv*2 + grp;

  float g1[4], be1[4];
  *(float4*)&g1[0]  = *(const float4*)(ln1_g + c*4);
  *(float4*)&be1[0] = *(const float4*)(ln1_b + c*4);

  uint2 qu = *(const uint2*)(val + ((size_t)(b*N_)*P_ + p)*D_ + c*4);
  float qv[4];
  bfu2(qu.x, qv[0], qv[1]); bfu2(qu.y, qv[2], qv[3]);
  float qp = 0.f;
  #pragma unroll
  for (int i = 0; i < 4; i++) qp += qv[i]*qv[i];
  float qinv = 1.f / fmaxf(sqrtf(gred32(qp)), 1e-12f);

  float dotv[N_];
  float sv[N_][4];
  #pragma unroll
  for (int np = 0; np < 3; np++) {
    uint2 g[2][4]; float wm[2][4]; bool vld[2];
    // issue phase: 8 gathers for two views
    #pragma unroll
    for (int t = 0; t < 2; t++) {
      int n = np*2 + t;
      float2 uv = uvbuf[((size_t)(b*N_ + n))*P_ + p];
      float sx = uv.x, sy = uv.y;
      float x0f = floorf(sx), y0f = floorf(sy);
      float fx = sx - x0f, fy = sy - y0f;
      int x0 = (int)x0f, y0 = (int)y0f;
      const unsigned short* base = val + ((size_t)(b*N_+n)*P_)*D_ + c*4;
      #pragma unroll
      for (int k = 0; k < 4; k++) {
        int dx = k & 1, dy = k >> 1;
        int cx = x0 + dx, cy = y0 + dy;
        bool inb = (cx >= 0) && (cx <= WF_-1) && (cy >= 0) && (cy <= HF_-1);
        int icx = min(max(cx,0),WF_-1), icy = min(max(cy,0),HF_-1);
        wm[t][k] = inb ? (dx ? fx : 1.f-fx) * (dy ? fy : 1.f-fy) : 0.f;
        g[t][k] = *(const uint2*)(base + (size_t)(icy*WF_ + icx)*D_);
      }
      vld[t] = (sx >= 0.f) && (sx <= (float)(WF_-1)) && (sy >= 0.f) && (sy <= (float)(HF_-1));
    }
    // math phase
    #pragma unroll
    for (int t = 0; t < 2; t++) {
      int n = np*2 + t;
      float acc[4];
      #pragma unroll
      for (int i = 0; i < 4; i++) acc[i] = 0.f;
      #pragma unroll
      for (int k = 0; k < 4; k++) {
        float gg[4];
        bfu2(g[t][k].x, gg[0], gg[1]); bfu2(g[t][k].y, gg[2], gg[3]);
        float w = wm[t][k];
        #pragma unroll
        for (int i = 0; i < 4; i++) acc[i] += gg[i]*w;
      }
      float ssp = 0.f, qsp = 0.f;
      #pragma unroll
      for (int i = 0; i < 4; i++) { ssp += acc[i]*acc[i]; qsp += qv[i]*acc[i]; }
      float ss = gred32(ssp);
      float qs = gred32(qsp);
      float dn = qs * qinv / fmaxf(sqrtf(ss), 1e-12f);
      dotv[n] = vld[t] ? dn : 0.f;
      #pragma unroll
      for (int i = 0; i < 4; i++) sv[n][i] = acc[i];
    }
  }
  // softmax over n
  float mx = dotv[0];
  #pragma unroll
  for (int n = 1; n < N_; n++) mx = fmaxf(mx, dotv[n]);
  float e[N_]; float den = 0.f;
  #pragma unroll
  for (int n = 0; n < N_; n++) { e[n] = expf(dotv[n]-mx); den += e[n]; }
  float rden = 1.f/den;
  float z[4];
  #pragma unroll
  for (int i = 0; i < 4; i++) z[i] = qv[i];
  #pragma unroll
  for (int n = 0; n < N_; n++) {
    float a = e[n]*rden;
    #pragma unroll
    for (int i = 0; i < 4; i++) z[i] += a*sv[n][i];
  }
  // LN1
  float sp = 0.f;
  #pragma unroll
  for (int i = 0; i < 4; i++) sp += z[i];
  float mu = gred32(sp) * (1.f/128.f);
  float vp = 0.f;
  #pragma unroll
  for (int i = 0; i < 4; i++) { float d0 = z[i]-mu; vp += d0*d0; }
  float rs = rsqrtf(gred32(vp) * (1.f/128.f) + 1e-5f);
  unsigned int ow[2];
  #pragma unroll
  for (int i = 0; i < 2; i++) {
    float o0 = (z[2*i]-mu)*rs*g1[2*i] + be1[2*i];
    float o1 = (z[2*i+1]-mu)*rs*g1[2*i+1] + be1[2*i+1];
    ow[i] = (unsigned int)f2bf(o0) | ((unsigned int)f2bf(o1) << 16);
  }
  *(uint2*)(zbuf + ((size_t)b*P_ + p)*D_ + c*4) = make_uint2(ow[0], ow[1]);
}

// ---------------------------------------------------------------------------
// mlp (MFMA bf16): 32-p blocks (960 total), GEMM cols split across wave pairs,
// LN2 via cross-wave LDS partials. Output transposed via LDS.
// ---------------------------------------------------------------------------
__global__ __launch_bounds__(256) void mlp_kernel(const unsigned short* __restrict__ zbuf,
    const unsigned short* __restrict__ w1s, const float* __restrict__ b1,
    const unsigned short* __restrict__ w2s, const float* __restrict__ b2,
    const float* __restrict__ ln2_g, const float* __restrict__ ln2_b,
    float* __restrict__ out) {
  __shared__ __align__(16) char smem[26112];
  unsigned short* zt = (unsigned short*)smem;            // 32*136*2 = 8704 B
  unsigned short* ht = (unsigned short*)(smem + 8704);   // 32*264*2 = 16896 B
  float* lnp = (float*)(smem + 25600);                   // [2][32][2] fp32 = 512 B
  float* yt = (float*)smem;                              // 128*34*4 = 17408 B (alias)

  int tid = threadIdx.x;
  int b = blockIdx.y;
  int p0 = blockIdx.x * 32;
  int ln = tid & 63, wv = tid >> 6;
  int m = ln & 15, q = ln >> 4;
  int h = wv >> 1, ch2 = wv & 1;   // p-half, col-half

  #pragma unroll
  for (int i = 0; i < 2; i++) {
    int idx = tid + i*256;          // 512 = 32 p x 16 chunks of 8 d
    int pp = idx >> 4, ch = idx & 15;
    *(uint4*)&zt[pp*136 + ch*8] = *(const uint4*)(zbuf + ((size_t)b*P_ + p0 + pp)*D_ + ch*8);
  }
  __syncthreads();

  // GEMM1: 16 p x 128 cols per wave (8 col tiles), K=128
  floatx4 a1[8];
  #pragma unroll
  for (int j = 0; j < 8; j++) a1[j] = (floatx4){0.f,0.f,0.f,0.f};
  #pragma unroll
  for (int kc = 0; kc < 4; kc++) {
    short8 af = *(const short8*)&zt[(h*16+m)*136 + kc*32 + q*8];
    #pragma unroll
    for (int j = 0; j < 8; j++) {
      int dt = ch2*8 + j;
      short8 bfg = *(const short8*)(w1s + (((size_t)kc*16 + dt)*64 + ln)*8);
      a1[j] = __builtin_amdgcn_mfma_f32_16x16x32_bf16(af, bfg, a1[j], 0, 0, 0);
    }
  }
  #pragma unroll
  for (int j = 0; j < 8; j++) {
    int dt = ch2*8 + j;
    float bb = b1[dt*16 + m];
    #pragma unroll
    for (int r = 0; r < 4; r++) {
      float x = a1[j][r] + bb;
      float hv = 0.5f*x*(1.f + erff(x*0.70710678118654752f));
      ht[(h*16 + q*4 + r)*264 + dt*16 + m] = f2bf(hv);
    }
  }
  __syncthreads();

  // GEMM2: 16 p x 64 cols per wave (4 col tiles), K=256
  floatx4 a2[4];
  #pragma unroll
  for (int j = 0; j < 4; j++) a2[j] = (floatx4){0.f,0.f,0.f,0.f};
  #pragma unroll
  for (int kc = 0; kc < 8; kc++) {
    short8 af = *(const short8*)&ht[(h*16+m)*264 + kc*32 + q*8];
    #pragma unroll
    for (int j = 0; j < 4; j++) {
      int dt = ch2*4 + j;
      short8 bfg = *(const short8*)(w2s + (((size_t)kc*8 + dt)*64 + ln)*8);
      a2[j] = __builtin_amdgcn_mfma_f32_16x16x32_bf16(af, bfg, a2[j], 0, 0, 0);
    }
  }
  // bias + residual
  float y[4][4];
  #pragma unroll
  for (int j = 0; j < 4; j++) {
    int dt = ch2*4 + j;
    float bb = b2[dt*16 + m];
    #pragma unroll
    for (int r = 0; r < 4; r++) {
      int pp = h*16 + q*4 + r;
      y[j][r] = a2[j][r] + bb + bf2f(zt[pp*136 + dt*16 + m]);
    }
  }
  // LN2 partials (each wave covers 64 of 128 cols)
  #pragma unroll
  for (int r = 0; r < 4; r++) {
    float sp = 0.f, sq = 0.f;
    #pragma unroll
    for (int j = 0; j < 4; j++) { sp += y[j][r]; sq += y[j][r]*y[j][r]; }
    sp = gred_sum(sp); sq = gred_sum(sq);
    if (m == 0) {
      int pl = h*16 + q*4 + r;
      lnp[(ch2*32 + pl)*2 + 0] = sp;
      lnp[(ch2*32 + pl)*2 + 1] = sq;
    }
  }
  __syncthreads();
  float mu_[4], rs_[4];
  #pragma unroll
  for (int r = 0; r < 4; r++) {
    int pl = h*16 + q*4 + r;
    float sum = lnp[pl*2]     + lnp[(32+pl)*2];
    float ssq = lnp[pl*2 + 1] + lnp[(32+pl)*2 + 1];
    float mu = sum * (1.f/128.f);
    float var = fmaxf(ssq * (1.f/128.f) - mu*mu, 0.f);
    mu_[r] = mu; rs_[r] = rsqrtf(var + 1e-5f);
  }
  float gg[4], be[4];
  #pragma unroll
  for (int j = 0; j < 4; j++) {
    int d = (ch2*4 + j)*16 + m;
    gg[j] = ln2_g[d]; be[j] = ln2_b[d];
  }
  #pragma unroll
  for (int j = 0; j < 4; j++)
    #pragma unroll
    for (int r = 0; r < 4; r++)
      y[j][r] = (y[j][r] - mu_[r])*rs_[r]*gg[j] + be[j];
  __syncthreads();   // zt/ht/lnp reads done before yt alias writes
  #pragma unroll
  for (int j = 0; j < 4; j++)
    #pragma unroll
    for (int r = 0; r < 4; r++)
      yt[((ch2*4 + j)*16 + m)*34 + h*16 + q*4 + r] = y[j][r];
  __syncthreads();

  // transposed write: out[b, d, p0..p0+31]
  #pragma unroll
  for (int i = 0; i < 8; i++) {
    int idx = tid + i*256;    // 2048 float2 units = 128 d x 16
    int d = idx >> 4, pu = idx & 15;
    *(float2*)(out + ((size_t)(b*D_ + d))*P_ + p0 + pu*2) = *(float2*)&yt[d*34 + pu*2];
  }
}

// ---------------------------------------------------------------------------
extern "C" void kernel_launch(void* const* d_in, const int* in_sizes, int n_in,
                              void* d_out, int out_size, void* d_ws, size_t ws_size,
                              hipStream_t stream) {
  (void)in_sizes; (void)n_in; (void)out_size; (void)ws_size;
  const float* feature   = (const float*)d_in[0];
  const float* I_src     = (const float*)d_in[1];
  const float* I_tar_inv = (const float*)d_in[2];
  const float* E         = (const float*)d_in[3];
  const float* dis       = (const float*)d_in[4];
  const float* norm_vec  = (const float*)d_in[5];
  const float* bn_gamma  = (const float*)d_in[6];
  const float* bn_beta   = (const float*)d_in[7];
  const float* bn_mean   = (const float*)d_in[8];
  const float* bn_var    = (const float*)d_in[9];
  const float* conv_w    = (const float*)d_in[10];
  const float* ln1_g     = (const float*)d_in[11];
  const float* ln1_b     = (const float*)d_in[12];
  const float* mlp_w1    = (const float*)d_in[13];
  const float* mlp_b1    = (const float*)d_in[14];
  const float* mlp_w2    = (const float*)d_in[15];
  const float* mlp_b2    = (const float*)d_in[16];
  const float* ln2_g     = (const float*)d_in[17];
  const float* ln2_b     = (const float*)d_in[18];
  float* out = (float*)d_out;

  char* ws = (char*)d_ws;
  float* bnscale       = (float*)(ws + 0);
  float* bnbias        = (float*)(ws + 1024);
  float* Hm            = (float*)(ws + 2048);
  unsigned short* wswz = (unsigned short*)(ws + 4096);       // 64 KB
  unsigned short* w1s  = (unsigned short*)(ws + 69632);      // 64 KB
  unsigned short* w2s  = (unsigned short*)(ws + 135168);     // 64 KB
  float2* uvbuf        = (float2*)(ws + 200704);             // 1.47 MB
  unsigned short* val  = (unsigned short*)(ws + 1675264);              // bf16 (B,N,P,D) 47.2 MB
  unsigned short* zbuf = (unsigned short*)(ws + 1675264 + 47185920ULL);// bf16 (B,P,D) 7.9 MB

  hipLaunchKernelGGL(prep_kernel, dim3(1), dim3(256), 0, stream,
                     I_src, I_tar_inv, E, dis, norm_vec,
                     bn_gamma, bn_beta, bn_mean, bn_var, bnscale, bnbias, Hm);
  hipLaunchKernelGGL(uv_kernel, dim3(720), dim3(256), 0, stream, Hm, uvbuf);
  hipLaunchKernelGGL(swizzle_w_kernel, dim3(128), dim3(256), 0, stream, conv_w, wswz);
  hipLaunchKernelGGL(swizzle_mlp_kernel, dim3(256), dim3(256), 0, stream,
                     mlp_w1, mlp_w2, w1s, w2s);
  hipLaunchKernelGGL(conv_kernel, dim3(120, 24), dim3(256), 0, stream,
                     feature, wswz, bnscale, bnbias, val);
  hipLaunchKernelGGL(att_kernel, dim3(960, 4), dim3(256), 0, stream,
                     val, uvbuf, ln1_g, ln1_b, zbuf);
  hipLaunchKernelGGL(mlp_kernel, dim3(240, 4), dim3(256), 0, stream,
                     zbuf, w1s, mlp_b1, w2s, mlp_b2, ln2_g, ln2_b, out);
}

// Round 2
// 359.319 us; speedup vs baseline: 1.0287x; 1.0016x over previous
//
#include <hip/hip_runtime.h>
#include <hip/hip_bf16.h>
#include <math.h>

#define B_ 4
#define N_ 6
#define FD_ 256
#define D_ 128
#define HF_ 64
#define WF_ 120
#define P_ (HF_*WF_)   // 7680

typedef __attribute__((ext_vector_type(8))) short short8;
typedef __attribute__((ext_vector_type(4))) float floatx4;
typedef __attribute__((ext_vector_type(4))) unsigned int uint4e;

__device__ inline float gred_sum(float v) {   // sum within 16-lane group
  v += __shfl_xor(v, 1); v += __shfl_xor(v, 2);
  v += __shfl_xor(v, 4); v += __shfl_xor(v, 8);
  return v;
}

__device__ inline float gred32(float v) {     // sum within 32-lane group
  v += __shfl_xor(v, 1); v += __shfl_xor(v, 2);
  v += __shfl_xor(v, 4); v += __shfl_xor(v, 8);
  v += __shfl_xor(v, 16);
  return v;
}

__device__ inline unsigned short f2bf(float f) {
  unsigned int u = __builtin_bit_cast(unsigned int, f);
  u += 0x7fffu + ((u >> 16) & 1u);   // RNE
  return (unsigned short)(u >> 16);
}
__device__ inline float bf2f(unsigned short h) {
  return __builtin_bit_cast(float, ((unsigned int)h) << 16);
}
__device__ inline void bfu2(unsigned int u, float& lo, float& hi) {
  lo = __builtin_bit_cast(float, u << 16);
  hi = __builtin_bit_cast(float, u & 0xffff0000u);
}

// LDS-only barrier: orders LDS ops across the workgroup WITHOUT draining
// outstanding global loads (vmcnt), unlike __syncthreads() which compiles
// to s_waitcnt vmcnt(0) lgkmcnt(0); s_barrier. The "memory" clobber pins
// all memory ops on the correct side at the compiler level.
__device__ inline void lds_barrier() {
  asm volatile("s_waitcnt lgkmcnt(0)\n\ts_barrier" ::: "memory");
}

// ---------------------------------------------------------------------------
// prep: BN fold + homographies
// ---------------------------------------------------------------------------
__global__ void prep_kernel(const float* __restrict__ I_src, const float* __restrict__ I_tar_inv,
                            const float* __restrict__ E, const float* __restrict__ dis,
                            const float* __restrict__ norm_vec,
                            const float* __restrict__ bn_gamma, const float* __restrict__ bn_beta,
                            const float* __restrict__ bn_mean, const float* __restrict__ bn_var,
                            float* __restrict__ bnscale, float* __restrict__ bnbias,
                            float* __restrict__ Hm) {
  int t = threadIdx.x;
  if (t < FD_) {
    float s = bn_gamma[t] * rsqrtf(bn_var[t] + 1e-5f);
    bnscale[t] = s;
    bnbias[t] = bn_beta[t] - bn_mean[t] * s;
  }
  if (t < B_*N_) {
    int b = t / N_;
    const float* e = E + t*16;
    const float* nv = norm_vec + b*3;
    float inv_dis = 1.0f / dis[0];
    float M[9];
    #pragma unroll
    for (int r = 0; r < 3; r++)
      #pragma unroll
      for (int c = 0; c < 3; c++)
        M[r*3+c] = e[r*4+c] - e[r*4+3]*nv[c]*inv_dis;
    const float* Is = I_src + t*9;
    float A[9];
    #pragma unroll
    for (int r = 0; r < 3; r++)
      #pragma unroll
      for (int c = 0; c < 3; c++)
        A[r*3+c] = Is[r*3+0]*M[0*3+c] + Is[r*3+1]*M[1*3+c] + Is[r*3+2]*M[2*3+c];
    const float* It = I_tar_inv + b*9;
    #pragma unroll
    for (int r = 0; r < 3; r++)
      #pragma unroll
      for (int c = 0; c < 3; c++)
        Hm[t*9 + r*3+c] = A[r*3+0]*It[0*3+c] + A[r*3+1]*It[1*3+c] + A[r*3+2]*It[2*3+c];
  }
}

// ---------------------------------------------------------------------------
// uv precompute: sx,sy per (b,n,p). 184320 = 720*256 exactly.
// ---------------------------------------------------------------------------
__global__ void uv_kernel(const float* __restrict__ Hm, float2* __restrict__ uvbuf) {
  int t = blockIdx.x * 256 + threadIdx.x;
  int p  = t % P_;
  int bn = t / P_;
  int py = p / WF_, px = p - py*WF_;
  float pixx = (float)px * (960.f/119.f);
  float pixy = (float)py * (480.f/63.f);
  const float* H = Hm + bn*9;
  float hx = H[0]*pixx + H[1]*pixy + H[2];
  float hy = H[3]*pixx + H[4]*pixy + H[5];
  float hz = H[6]*pixx + H[7]*pixy + H[8];
  float sx = (hx/hz) * ((float)WF_/960.f);
  float sy = (hy/hz) * ((float)HF_/480.f);
  uvbuf[t] = make_float2(sx, sy);
}

// ---------------------------------------------------------------------------
// swizzle conv_w (D,FD) fp32 -> bf16 B-fragment order
// ---------------------------------------------------------------------------
__global__ void swizzle_w_kernel(const float* __restrict__ conv_w, unsigned short* __restrict__ wswz) {
  int t = blockIdx.x * 256 + threadIdx.x;   // 0..32767
  int j    =  t        & 7;
  int lane = (t >> 3)  & 63;
  int dt   = (t >> 9)  & 7;
  int kc   =  t >> 12;
  int d = dt*16 + (lane & 15);
  int k = kc*32 + (lane >> 4)*8 + j;
  wswz[t] = f2bf(conv_w[d*FD_ + k]);
}

// ---------------------------------------------------------------------------
// swizzle mlp weights to B-frag order bf16
// ---------------------------------------------------------------------------
__global__ void swizzle_mlp_kernel(const float* __restrict__ w1, const float* __restrict__ w2,
                                   unsigned short* __restrict__ w1s, unsigned short* __restrict__ w2s) {
  int t = blockIdx.x * 256 + threadIdx.x;   // 0..65535
  if (t < 32768) {
    int j    =  t        & 7;
    int lane = (t >> 3)  & 63;
    int dt   = (t >> 9)  & 15;
    int kc   =  t >> 13;
    int n = dt*16 + (lane & 15);
    int k = kc*32 + (lane >> 4)*8 + j;
    w1s[t] = f2bf(w1[k*256 + n]);
  } else {
    int u = t - 32768;
    int j    =  u        & 7;
    int lane = (u >> 3)  & 63;
    int dt   = (u >> 9)  & 7;
    int kc   =  u >> 12;
    int n = dt*16 + (lane & 15);
    int k = kc*32 + (lane >> 4)*8 + j;
    w2s[u] = f2bf(w2[k*128 + n]);
  }
}

// ---------------------------------------------------------------------------
// conv (MFMA): depth-2 register prefetch. In-loop barriers are LDS-only
// (s_waitcnt lgkmcnt(0); s_barrier) so the chunk kc+2 global loads genuinely
// stay in flight across the barrier instead of being drained by the
// vmcnt(0) that __syncthreads() emits. LDS double-buffer, ytile aliases
// apad (19.4 KB LDS -> 8 blocks/CU). block: 64 p x 128 d, 4 waves.
// ---------------------------------------------------------------------------
#define AST_ 36   // apad stride in shorts (72 B rows, 8B-aligned frag reads)
__global__ __launch_bounds__(256) void conv_kernel(const float* __restrict__ feature,
    const unsigned short* __restrict__ wswz, const float* __restrict__ bnscale,
    const float* __restrict__ bnbias, unsigned short* __restrict__ val) {
  __shared__ __align__(16) char csm[19968];
  unsigned short* apadA = (unsigned short*)csm;            // 64*36*2 = 4608 B
  unsigned short* apadB = (unsigned short*)(csm + 4608);   // 4608 B
  unsigned short* ytile = (unsigned short*)csm;            // 64*136*2 = 17408 B (alias)
  float* sbn = (float*)(csm + 17408);                      // 2048 B

  int tid = threadIdx.x;
  sbn[tid] = bnscale[tid]; sbn[256+tid] = bnbias[tid];

  int bn = blockIdx.y;
  int p0 = blockIdx.x * 64;
  const float* fbase2 = feature + (size_t)bn*FD_*P_ + p0;

  int K0 = tid >> 4;   // k-pair index within chunk
  int sp = (tid & 15) * 4;

  int ln = tid & 63, wv = tid >> 6;
  int m = ln & 15, q = ln >> 4;
  int row = wv*16 + m;

  float4 va[2], vb[2];
  // prolog loads: chunks 0,1
  {
    const float* fb0 = fbase2 + (size_t)(2*K0)*P_ + sp;
    va[0] = *(const float4*)fb0; vb[0] = *(const float4*)(fb0 + P_);
    const float* fb1 = fbase2 + (size_t)(32 + 2*K0)*P_ + sp;
    va[1] = *(const float4*)fb1; vb[1] = *(const float4*)(fb1 + P_);
  }
  __syncthreads();   // sbn visible

  floatx4 acc[8];
  #pragma unroll
  for (int dt = 0; dt < 8; dt++) acc[dt] = (floatx4){0.f,0.f,0.f,0.f};

  // pack chunk0 -> apadA
  {
    int k0 = 0;
    float s0 = sbn[k0+2*K0],   b0 = sbn[256+k0+2*K0];
    float s1 = sbn[k0+2*K0+1], b1 = sbn[256+k0+2*K0+1];
    float a0[4] = {va[0].x, va[0].y, va[0].z, va[0].w};
    float a1[4] = {vb[0].x, vb[0].y, vb[0].z, vb[0].w};
    #pragma unroll
    for (int i = 0; i < 4; i++) {
      unsigned int w = (unsigned int)f2bf(fmaxf(a0[i]*s0+b0, 0.f))
                     | ((unsigned int)f2bf(fmaxf(a1[i]*s1+b1, 0.f)) << 16);
      *(unsigned int*)&apadA[(sp+i)*AST_ + 2*K0] = w;
    }
  }

  #pragma unroll
  for (int kc = 0; kc < 8; kc++) {
    lds_barrier();   // LDS-only: does NOT drain the in-flight global loads
    // issue loads for chunk kc+2 (stay in flight across this whole iteration)
    if (kc + 2 < 8) {
      const float* fb = fbase2 + (size_t)((kc+2)*32 + 2*K0)*P_ + sp;
      va[kc&1] = *(const float4*)fb;
      vb[kc&1] = *(const float4*)(fb + P_);
    }
    // pack+write chunk kc+1 (its loads were issued a full iteration ago)
    if (kc + 1 < 8) {
      int s = (kc+1)&1;
      int k0 = (kc+1)*32;
      unsigned short* ap = ((kc+1)&1) ? apadB : apadA;
      float s0 = sbn[k0+2*K0],   b0 = sbn[256+k0+2*K0];
      float s1 = sbn[k0+2*K0+1], b1 = sbn[256+k0+2*K0+1];
      float a0[4] = {va[s].x, va[s].y, va[s].z, va[s].w};
      float a1[4] = {vb[s].x, vb[s].y, vb[s].z, vb[s].w};
      #pragma unroll
      for (int i = 0; i < 4; i++) {
        unsigned int w = (unsigned int)f2bf(fmaxf(a0[i]*s0+b0, 0.f))
                       | ((unsigned int)f2bf(fmaxf(a1[i]*s1+b1, 0.f)) << 16);
        *(unsigned int*)&ap[(sp+i)*AST_ + 2*K0] = w;
      }
    }
    // MFMA chunk kc
    unsigned short* rp = (kc&1) ? apadB : apadA;
    uint2 u0 = *(const uint2*)&rp[row*AST_ + q*8];
    uint2 u1 = *(const uint2*)&rp[row*AST_ + q*8 + 4];
    uint4e ua = {u0.x, u0.y, u1.x, u1.y};
    short8 af = __builtin_bit_cast(short8, ua);
    #pragma unroll
    for (int dt = 0; dt < 8; dt++) {
      short8 bfg = *(const short8*)(wswz + (((size_t)kc*8 + dt)*64 + ln)*8);
      acc[dt] = __builtin_amdgcn_mfma_f32_16x16x32_bf16(af, bfg, acc[dt], 0, 0, 0);
    }
  }
  __syncthreads();   // all apad reads done before ytile alias writes

  #pragma unroll
  for (int dt = 0; dt < 8; dt++)
    #pragma unroll
    for (int r = 0; r < 4; r++)
      ytile[(wv*16 + q*4 + r)*136 + dt*16 + m] = f2bf(acc[dt][r]);
  __syncthreads();
  #pragma unroll
  for (int i = 0; i < 4; i++) {
    int idx = tid + i*256;
    int pp = idx >> 4, ch = idx & 15;
    uint4 v = *(const uint4*)&ytile[pp*136 + ch*8];
    *(uint4*)(val + ((size_t)bn*P_ + p0 + pp)*D_ + ch*8) = v;
  }
}

// ---------------------------------------------------------------------------
// att v2: 32-lane group per point (4 ch/lane), 1 point per thread,
// 8 points/block, grid 960x4, gathers issued in n-pairs ahead of math,
// XCD-chunked blockIdx.x swizzle for val L2 locality.
// ---------------------------------------------------------------------------
__global__ __launch_bounds__(256, 4) void att_kernel(const unsigned short* __restrict__ val,
    const float2* __restrict__ uvbuf, const float* __restrict__ ln1_g,
    const float* __restrict__ ln1_b, unsigned short* __restrict__ zbuf) {
  int b = blockIdx.y;
  int bx = blockIdx.x;
  int tile = (bx & 7) * 120 + (bx >> 3);   // 960 tiles, 960%8==0 -> bijective
  int p0 = tile * 8;
  int tid = threadIdx.x;
  int ln = tid & 63, wv = tid >> 6;
  int grp = ln >> 5, c = ln & 31;          // 2 points per wave, 32 lanes each
  int p = p0 + wv*2 + grp;

  float g1[4], be1[4];
  *(float4*)&g1[0]  = *(const float4*)(ln1_g + c*4);
  *(float4*)&be1[0] = *(const float4*)(ln1_b + c*4);

  uint2 qu = *(const uint2*)(val + ((size_t)(b*N_)*P_ + p)*D_ + c*4);
  float qv[4];
  bfu2(qu.x, qv[0], qv[1]); bfu2(qu.y, qv[2], qv[3]);
  float qp = 0.f;
  #pragma unroll
  for (int i = 0; i < 4; i++) qp += qv[i]*qv[i];
  float qinv = 1.f / fmaxf(sqrtf(gred32(qp)), 1e-12f);

  float dotv[N_];
  float sv[N_][4];
  #pragma unroll
  for (int np = 0; np < 3; np++) {
    uint2 g[2][4]; float wm[2][4]; bool vld[2];
    // issue phase: 8 gathers for two views
    #pragma unroll
    for (int t = 0; t < 2; t++) {
      int n = np*2 + t;
      float2 uv = uvbuf[((size_t)(b*N_ + n))*P_ + p];
      float sx = uv.x, sy = uv.y;
      float x0f = floorf(sx), y0f = floorf(sy);
      float fx = sx - x0f, fy = sy - y0f;
      int x0 = (int)x0f, y0 = (int)y0f;
      const unsigned short* base = val + ((size_t)(b*N_+n)*P_)*D_ + c*4;
      #pragma unroll
      for (int k = 0; k < 4; k++) {
        int dx = k & 1, dy = k >> 1;
        int cx = x0 + dx, cy = y0 + dy;
        bool inb = (cx >= 0) && (cx <= WF_-1) && (cy >= 0) && (cy <= HF_-1);
        int icx = min(max(cx,0),WF_-1), icy = min(max(cy,0),HF_-1);
        wm[t][k] = inb ? (dx ? fx : 1.f-fx) * (dy ? fy : 1.f-fy) : 0.f;
        g[t][k] = *(const uint2*)(base + (size_t)(icy*WF_ + icx)*D_);
      }
      vld[t] = (sx >= 0.f) && (sx <= (float)(WF_-1)) && (sy >= 0.f) && (sy <= (float)(HF_-1));
    }
    // math phase
    #pragma unroll
    for (int t = 0; t < 2; t++) {
      int n = np*2 + t;
      float acc[4];
      #pragma unroll
      for (int i = 0; i < 4; i++) acc[i] = 0.f;
      #pragma unroll
      for (int k = 0; k < 4; k++) {
        float gg[4];
        bfu2(g[t][k].x, gg[0], gg[1]); bfu2(g[t][k].y, gg[2], gg[3]);
        float w = wm[t][k];
        #pragma unroll
        for (int i = 0; i < 4; i++) acc[i] += gg[i]*w;
      }
      float ssp = 0.f, qsp = 0.f;
      #pragma unroll
      for (int i = 0; i < 4; i++) { ssp += acc[i]*acc[i]; qsp += qv[i]*acc[i]; }
      float ss = gred32(ssp);
      float qs = gred32(qsp);
      float dn = qs * qinv / fmaxf(sqrtf(ss), 1e-12f);
      dotv[n] = vld[t] ? dn : 0.f;
      #pragma unroll
      for (int i = 0; i < 4; i++) sv[n][i] = acc[i];
    }
  }
  // softmax over n
  float mx = dotv[0];
  #pragma unroll
  for (int n = 1; n < N_; n++) mx = fmaxf(mx, dotv[n]);
  float e[N_]; float den = 0.f;
  #pragma unroll
  for (int n = 0; n < N_; n++) { e[n] = expf(dotv[n]-mx); den += e[n]; }
  float rden = 1.f/den;
  float z[4];
  #pragma unroll
  for (int i = 0; i < 4; i++) z[i] = qv[i];
  #pragma unroll
  for (int n = 0; n < N_; n++) {
    float a = e[n]*rden;
    #pragma unroll
    for (int i = 0; i < 4; i++) z[i] += a*sv[n][i];
  }
  // LN1
  float sp = 0.f;
  #pragma unroll
  for (int i = 0; i < 4; i++) sp += z[i];
  float mu = gred32(sp) * (1.f/128.f);
  float vp = 0.f;
  #pragma unroll
  for (int i = 0; i < 4; i++) { float d0 = z[i]-mu; vp += d0*d0; }
  float rs = rsqrtf(gred32(vp) * (1.f/128.f) + 1e-5f);
  unsigned int ow[2];
  #pragma unroll
  for (int i = 0; i < 2; i++) {
    float o0 = (z[2*i]-mu)*rs*g1[2*i] + be1[2*i];
    float o1 = (z[2*i+1]-mu)*rs*g1[2*i+1] + be1[2*i+1];
    ow[i] = (unsigned int)f2bf(o0) | ((unsigned int)f2bf(o1) << 16);
  }
  *(uint2*)(zbuf + ((size_t)b*P_ + p)*D_ + c*4) = make_uint2(ow[0], ow[1]);
}

// ---------------------------------------------------------------------------
// mlp (MFMA bf16): 32-p blocks (960 total), GEMM cols split across wave pairs,
// LN2 via cross-wave LDS partials. Output transposed via LDS.
// ---------------------------------------------------------------------------
__global__ __launch_bounds__(256) void mlp_kernel(const unsigned short* __restrict__ zbuf,
    const unsigned short* __restrict__ w1s, const float* __restrict__ b1,
    const unsigned short* __restrict__ w2s, const float* __restrict__ b2,
    const float* __restrict__ ln2_g, const float* __restrict__ ln2_b,
    float* __restrict__ out) {
  __shared__ __align__(16) char smem[26112];
  unsigned short* zt = (unsigned short*)smem;            // 32*136*2 = 8704 B
  unsigned short* ht = (unsigned short*)(smem + 8704);   // 32*264*2 = 16896 B
  float* lnp = (float*)(smem + 25600);                   // [2][32][2] fp32 = 512 B
  float* yt = (float*)smem;                              // 128*34*4 = 17408 B (alias)

  int tid = threadIdx.x;
  int b = blockIdx.y;
  int p0 = blockIdx.x * 32;
  int ln = tid & 63, wv = tid >> 6;
  int m = ln & 15, q = ln >> 4;
  int h = wv >> 1, ch2 = wv & 1;   // p-half, col-half

  #pragma unroll
  for (int i = 0; i < 2; i++) {
    int idx = tid + i*256;          // 512 = 32 p x 16 chunks of 8 d
    int pp = idx >> 4, ch = idx & 15;
    *(uint4*)&zt[pp*136 + ch*8] = *(const uint4*)(zbuf + ((size_t)b*P_ + p0 + pp)*D_ + ch*8);
  }
  __syncthreads();

  // GEMM1: 16 p x 128 cols per wave (8 col tiles), K=128
  floatx4 a1[8];
  #pragma unroll
  for (int j = 0; j < 8; j++) a1[j] = (floatx4){0.f,0.f,0.f,0.f};
  #pragma unroll
  for (int kc = 0; kc < 4; kc++) {
    short8 af = *(const short8*)&zt[(h*16+m)*136 + kc*32 + q*8];
    #pragma unroll
    for (int j = 0; j < 8; j++) {
      int dt = ch2*8 + j;
      short8 bfg = *(const short8*)(w1s + (((size_t)kc*16 + dt)*64 + ln)*8);
      a1[j] = __builtin_amdgcn_mfma_f32_16x16x32_bf16(af, bfg, a1[j], 0, 0, 0);
    }
  }
  #pragma unroll
  for (int j = 0; j < 8; j++) {
    int dt = ch2*8 + j;
    float bb = b1[dt*16 + m];
    #pragma unroll
    for (int r = 0; r < 4; r++) {
      float x = a1[j][r] + bb;
      float hv = 0.5f*x*(1.f + erff(x*0.70710678118654752f));
      ht[(h*16 + q*4 + r)*264 + dt*16 + m] = f2bf(hv);
    }
  }
  __syncthreads();

  // GEMM2: 16 p x 64 cols per wave (4 col tiles), K=256
  floatx4 a2[4];
  #pragma unroll
  for (int j = 0; j < 4; j++) a2[j] = (floatx4){0.f,0.f,0.f,0.f};
  #pragma unroll
  for (int kc = 0; kc < 8; kc++) {
    short8 af = *(const short8*)&ht[(h*16+m)*264 + kc*32 + q*8];
    #pragma unroll
    for (int j = 0; j < 4; j++) {
      int dt = ch2*4 + j;
      short8 bfg = *(const short8*)(w2s + (((size_t)kc*8 + dt)*64 + ln)*8);
      a2[j] = __builtin_amdgcn_mfma_f32_16x16x32_bf16(af, bfg, a2[j], 0, 0, 0);
    }
  }
  // bias + residual
  float y[4][4];
  #pragma unroll
  for (int j = 0; j < 4; j++) {
    int dt = ch2*4 + j;
    float bb = b2[dt*16 + m];
    #pragma unroll
    for (int r = 0; r < 4; r++) {
      int pp = h*16 + q*4 + r;
      y[j][r] = a2[j][r] + bb + bf2f(zt[pp*136 + dt*16 + m]);
    }
  }
  // LN2 partials (each wave covers 64 of 128 cols)
  #pragma unroll
  for (int r = 0; r < 4; r++) {
    float sp = 0.f, sq = 0.f;
    #pragma unroll
    for (int j = 0; j < 4; j++) { sp += y[j][r]; sq += y[j][r]*y[j][r]; }
    sp = gred_sum(sp); sq = gred_sum(sq);
    if (m == 0) {
      int pl = h*16 + q*4 + r;
      lnp[(ch2*32 + pl)*2 + 0] = sp;
      lnp[(ch2*32 + pl)*2 + 1] = sq;
    }
  }
  __syncthreads();
  float mu_[4], rs_[4];
  #pragma unroll
  for (int r = 0; r < 4; r++) {
    int pl = h*16 + q*4 + r;
    float sum = lnp[pl*2]     + lnp[(32+pl)*2];
    float ssq = lnp[pl*2 + 1] + lnp[(32+pl)*2 + 1];
    float mu = sum * (1.f/128.f);
    float var = fmaxf(ssq * (1.f/128.f) - mu*mu, 0.f);
    mu_[r] = mu; rs_[r] = rsqrtf(var + 1e-5f);
  }
  float gg[4], be[4];
  #pragma unroll
  for (int j = 0; j < 4; j++) {
    int d = (ch2*4 + j)*16 + m;
    gg[j] = ln2_g[d]; be[j] = ln2_b[d];
  }
  #pragma unroll
  for (int j = 0; j < 4; j++)
    #pragma unroll
    for (int r = 0; r < 4; r++)
      y[j][r] = (y[j][r] - mu_[r])*rs_[r]*gg[j] + be[j];
  __syncthreads();   // zt/ht/lnp reads done before yt alias writes
  #pragma unroll
  for (int j = 0; j < 4; j++)
    #pragma unroll
    for (int r = 0; r < 4; r++)
      yt[((ch2*4 + j)*16 + m)*34 + h*16 + q*4 + r] = y[j][r];
  __syncthreads();

  // transposed write: out[b, d, p0..p0+31]
  #pragma unroll
  for (int i = 0; i < 8; i++) {
    int idx = tid + i*256;    // 2048 float2 units = 128 d x 16
    int d = idx >> 4, pu = idx & 15;
    *(float2*)(out + ((size_t)(b*D_ + d))*P_ + p0 + pu*2) = *(float2*)&yt[d*34 + pu*2];
  }
}

// ---------------------------------------------------------------------------
extern "C" void kernel_launch(void* const* d_in, const int* in_sizes, int n_in,
                              void* d_out, int out_size, void* d_ws, size_t ws_size,
                              hipStream_t stream) {
  (void)in_sizes; (void)n_in; (void)out_size; (void)ws_size;
  const float* feature   = (const float*)d_in[0];
  const float* I_src     = (const float*)d_in[1];
  const float* I_tar_inv = (const float*)d_in[2];
  const float* E         = (const float*)d_in[3];
  const float* dis       = (const float*)d_in[4];
  const float* norm_vec  = (const float*)d_in[5];
  const float* bn_gamma  = (const float*)d_in[6];
  const float* bn_beta   = (const float*)d_in[7];
  const float* bn_mean   = (const float*)d_in[8];
  const float* bn_var    = (const float*)d_in[9];
  const float* conv_w    = (const float*)d_in[10];
  const float* ln1_g     = (const float*)d_in[11];
  const float* ln1_b     = (const float*)d_in[12];
  const float* mlp_w1    = (const float*)d_in[13];
  const float* mlp_b1    = (const float*)d_in[14];
  const float* mlp_w2    = (const float*)d_in[15];
  const float* mlp_b2    = (const float*)d_in[16];
  const float* ln2_g     = (const float*)d_in[17];
  const float* ln2_b     = (const float*)d_in[18];
  float* out = (float*)d_out;

  char* ws = (char*)d_ws;
  float* bnscale       = (float*)(ws + 0);
  float* bnbias        = (float*)(ws + 1024);
  float* Hm            = (float*)(ws + 2048);
  unsigned short* wswz = (unsigned short*)(ws + 4096);       // 64 KB
  unsigned short* w1s  = (unsigned short*)(ws + 69632);      // 64 KB
  unsigned short* w2s  = (unsigned short*)(ws + 135168);     // 64 KB
  float2* uvbuf        = (float2*)(ws + 200704);             // 1.47 MB
  unsigned short* val  = (unsigned short*)(ws + 1675264);              // bf16 (B,N,P,D) 47.2 MB
  unsigned short* zbuf = (unsigned short*)(ws + 1675264 + 47185920ULL);// bf16 (B,P,D) 7.9 MB

  hipLaunchKernelGGL(prep_kernel, dim3(1), dim3(256), 0, stream,
                     I_src, I_tar_inv, E, dis, norm_vec,
                     bn_gamma, bn_beta, bn_mean, bn_var, bnscale, bnbias, Hm);
  hipLaunchKernelGGL(uv_kernel, dim3(720), dim3(256), 0, stream, Hm, uvbuf);
  hipLaunchKernelGGL(swizzle_w_kernel, dim3(128), dim3(256), 0, stream, conv_w, wswz);
  hipLaunchKernelGGL(swizzle_mlp_kernel, dim3(256), dim3(256), 0, stream,
                     mlp_w1, mlp_w2, w1s, w2s);
  hipLaunchKernelGGL(conv_kernel, dim3(120, 24), dim3(256), 0, stream,
                     feature, wswz, bnscale, bnbias, val);
  hipLaunchKernelGGL(att_kernel, dim3(960, 4), dim3(256), 0, stream,
                     val, uvbuf, ln1_g, ln1_b, zbuf);
  hipLaunchKernelGGL(mlp_kernel, dim3(240, 4), dim3(256), 0, stream,
                     zbuf, w1s, mlp_b1, w2s, mlp_b2, ln2_g, ln2_b, out);
}

// Round 3
// 358.631 us; speedup vs baseline: 1.0306x; 1.0019x over previous
//
#include <hip/hip_runtime.h>
#include <hip/hip_bf16.h>
#include <math.h>

#define B_ 4
#define N_ 6
#define FD_ 256
#define D_ 128
#define HF_ 64
#define WF_ 120
#define P_ (HF_*WF_)   // 7680

typedef __attribute__((ext_vector_type(8))) short short8;
typedef __attribute__((ext_vector_type(4))) float floatx4;
typedef __attribute__((ext_vector_type(4))) unsigned int uint4e;

__device__ inline float gred_sum(float v) {   // sum within 16-lane group
  v += __shfl_xor(v, 1); v += __shfl_xor(v, 2);
  v += __shfl_xor(v, 4); v += __shfl_xor(v, 8);
  return v;
}

__device__ inline float gred32(float v) {     // sum within 32-lane group
  v += __shfl_xor(v, 1); v += __shfl_xor(v, 2);
  v += __shfl_xor(v, 4); v += __shfl_xor(v, 8);
  v += __shfl_xor(v, 16);
  return v;
}

__device__ inline unsigned short f2bf(float f) {
  unsigned int u = __builtin_bit_cast(unsigned int, f);
  u += 0x7fffu + ((u >> 16) & 1u);   // RNE
  return (unsigned short)(u >> 16);
}
__device__ inline float bf2f(unsigned short h) {
  return __builtin_bit_cast(float, ((unsigned int)h) << 16);
}
__device__ inline void bfu2(unsigned int u, float& lo, float& hi) {
  lo = __builtin_bit_cast(float, u << 16);
  hi = __builtin_bit_cast(float, u & 0xffff0000u);
}

// LDS-only barrier: orders LDS ops across the workgroup WITHOUT draining
// outstanding global loads (vmcnt). R1 A/B vs __syncthreads: neutral
// (TLP at 8 blocks/CU already hides the drain) — kept, harmless.
__device__ inline void lds_barrier() {
  asm volatile("s_waitcnt lgkmcnt(0)\n\ts_barrier" ::: "memory");
}

// ---------------------------------------------------------------------------
// setup: one kernel for uv precompute (homography computed per-thread,
// identical fp32 arithmetic to the old prep kernel) + conv_w swizzle +
// mlp weight swizzles. 1104 blocks = 720 uv + 128 swz_w + 256 swz_mlp.
// ---------------------------------------------------------------------------
__global__ __launch_bounds__(256) void setup_kernel(
    const float* __restrict__ I_src, const float* __restrict__ I_tar_inv,
    const float* __restrict__ E, const float* __restrict__ dis,
    const float* __restrict__ norm_vec,
    const float* __restrict__ conv_w, const float* __restrict__ w1,
    const float* __restrict__ w2,
    float2* __restrict__ uvbuf, unsigned short* __restrict__ wswz,
    unsigned short* __restrict__ w1s, unsigned short* __restrict__ w2s) {
  int bx = blockIdx.x;
  int tid = threadIdx.x;
  if (bx < 720) {
    // ---- uv part ----
    int t = bx*256 + tid;
    int p  = t % P_;
    int bn = t / P_;
    int b  = bn / N_;
    // homography (identical arithmetic to old prep_kernel)
    const float* e  = E + bn*16;
    const float* nv = norm_vec + b*3;
    float inv_dis = 1.0f / dis[0];
    float M[9];
    #pragma unroll
    for (int r = 0; r < 3; r++)
      #pragma unroll
      for (int c = 0; c < 3; c++)
        M[r*3+c] = e[r*4+c] - e[r*4+3]*nv[c]*inv_dis;
    const float* Is = I_src + bn*9;
    float A[9];
    #pragma unroll
    for (int r = 0; r < 3; r++)
      #pragma unroll
      for (int c = 0; c < 3; c++)
        A[r*3+c] = Is[r*3+0]*M[0*3+c] + Is[r*3+1]*M[1*3+c] + Is[r*3+2]*M[2*3+c];
    const float* It = I_tar_inv + b*9;
    float H[9];
    #pragma unroll
    for (int r = 0; r < 3; r++)
      #pragma unroll
      for (int c = 0; c < 3; c++)
        H[r*3+c] = A[r*3+0]*It[0*3+c] + A[r*3+1]*It[1*3+c] + A[r*3+2]*It[2*3+c];
    int py = p / WF_, px = p - py*WF_;
    float pixx = (float)px * (960.f/119.f);
    float pixy = (float)py * (480.f/63.f);
    float hx = H[0]*pixx + H[1]*pixy + H[2];
    float hy = H[3]*pixx + H[4]*pixy + H[5];
    float hz = H[6]*pixx + H[7]*pixy + H[8];
    float sx = (hx/hz) * ((float)WF_/960.f);
    float sy = (hy/hz) * ((float)HF_/480.f);
    uvbuf[t] = make_float2(sx, sy);
  } else if (bx < 848) {
    // ---- conv_w swizzle ----
    int t = (bx-720)*256 + tid;   // 0..32767
    int j    =  t        & 7;
    int lane = (t >> 3)  & 63;
    int dt   = (t >> 9)  & 7;
    int kc   =  t >> 12;
    int d = dt*16 + (lane & 15);
    int k = kc*32 + (lane >> 4)*8 + j;
    wswz[t] = f2bf(conv_w[d*FD_ + k]);
  } else {
    // ---- mlp weight swizzles ----
    int t = (bx-848)*256 + tid;   // 0..65535
    if (t < 32768) {
      int j    =  t        & 7;
      int lane = (t >> 3)  & 63;
      int dt   = (t >> 9)  & 15;
      int kc   =  t >> 13;
      int n = dt*16 + (lane & 15);
      int k = kc*32 + (lane >> 4)*8 + j;
      w1s[t] = f2bf(w1[k*256 + n]);
    } else {
      int u = t - 32768;
      int j    =  u        & 7;
      int lane = (u >> 3)  & 63;
      int dt   = (u >> 9)  & 7;
      int kc   =  u >> 12;
      int n = dt*16 + (lane & 15);
      int k = kc*32 + (lane >> 4)*8 + j;
      w2s[u] = f2bf(w2[k*128 + n]);
    }
  }
}

// ---------------------------------------------------------------------------
// conv (MFMA): depth-2 register prefetch, LDS-only in-loop barriers,
// LDS double-buffer, ytile aliases apad (19.4 KB LDS -> 8 blocks/CU).
// BN fold computed inline (was prep_kernel). block: 64 p x 128 d, 4 waves.
// ---------------------------------------------------------------------------
#define AST_ 36   // apad stride in shorts (72 B rows, 8B-aligned frag reads)
__global__ __launch_bounds__(256) void conv_kernel(const float* __restrict__ feature,
    const unsigned short* __restrict__ wswz,
    const float* __restrict__ bn_gamma, const float* __restrict__ bn_beta,
    const float* __restrict__ bn_mean, const float* __restrict__ bn_var,
    unsigned short* __restrict__ val) {
  __shared__ __align__(16) char csm[19968];
  unsigned short* apadA = (unsigned short*)csm;            // 64*36*2 = 4608 B
  unsigned short* apadB = (unsigned short*)(csm + 4608);   // 4608 B
  unsigned short* ytile = (unsigned short*)csm;            // 64*136*2 = 17408 B (alias)
  float* sbn = (float*)(csm + 17408);                      // 2048 B

  int tid = threadIdx.x;
  {
    float s = bn_gamma[tid] * rsqrtf(bn_var[tid] + 1e-5f);
    sbn[tid] = s;
    sbn[256+tid] = bn_beta[tid] - bn_mean[tid] * s;
  }

  int bn = blockIdx.y;
  int p0 = blockIdx.x * 64;
  const float* fbase2 = feature + (size_t)bn*FD_*P_ + p0;

  int K0 = tid >> 4;   // k-pair index within chunk
  int sp = (tid & 15) * 4;

  int ln = tid & 63, wv = tid >> 6;
  int m = ln & 15, q = ln >> 4;
  int row = wv*16 + m;

  float4 va[2], vb[2];
  // prolog loads: chunks 0,1
  {
    const float* fb0 = fbase2 + (size_t)(2*K0)*P_ + sp;
    va[0] = *(const float4*)fb0; vb[0] = *(const float4*)(fb0 + P_);
    const float* fb1 = fbase2 + (size_t)(32 + 2*K0)*P_ + sp;
    va[1] = *(const float4*)fb1; vb[1] = *(const float4*)(fb1 + P_);
  }
  __syncthreads();   // sbn visible

  floatx4 acc[8];
  #pragma unroll
  for (int dt = 0; dt < 8; dt++) acc[dt] = (floatx4){0.f,0.f,0.f,0.f};

  // pack chunk0 -> apadA
  {
    int k0 = 0;
    float s0 = sbn[k0+2*K0],   b0 = sbn[256+k0+2*K0];
    float s1 = sbn[k0+2*K0+1], b1 = sbn[256+k0+2*K0+1];
    float a0[4] = {va[0].x, va[0].y, va[0].z, va[0].w};
    float a1[4] = {vb[0].x, vb[0].y, vb[0].z, vb[0].w};
    #pragma unroll
    for (int i = 0; i < 4; i++) {
      unsigned int w = (unsigned int)f2bf(fmaxf(a0[i]*s0+b0, 0.f))
                     | ((unsigned int)f2bf(fmaxf(a1[i]*s1+b1, 0.f)) << 16);
      *(unsigned int*)&apadA[(sp+i)*AST_ + 2*K0] = w;
    }
  }

  #pragma unroll
  for (int kc = 0; kc < 8; kc++) {
    lds_barrier();   // LDS-only: does NOT drain the in-flight global loads
    // issue loads for chunk kc+2 (stay in flight across this whole iteration)
    if (kc + 2 < 8) {
      const float* fb = fbase2 + (size_t)((kc+2)*32 + 2*K0)*P_ + sp;
      va[kc&1] = *(const float4*)fb;
      vb[kc&1] = *(const float4*)(fb + P_);
    }
    // pack+write chunk kc+1 (its loads were issued a full iteration ago)
    if (kc + 1 < 8) {
      int s = (kc+1)&1;
      int k0 = (kc+1)*32;
      unsigned short* ap = ((kc+1)&1) ? apadB : apadA;
      float s0 = sbn[k0+2*K0],   b0 = sbn[256+k0+2*K0];
      float s1 = sbn[k0+2*K0+1], b1 = sbn[256+k0+2*K0+1];
      float a0[4] = {va[s].x, va[s].y, va[s].z, va[s].w};
      float a1[4] = {vb[s].x, vb[s].y, vb[s].z, vb[s].w};
      #pragma unroll
      for (int i = 0; i < 4; i++) {
        unsigned int w = (unsigned int)f2bf(fmaxf(a0[i]*s0+b0, 0.f))
                       | ((unsigned int)f2bf(fmaxf(a1[i]*s1+b1, 0.f)) << 16);
        *(unsigned int*)&ap[(sp+i)*AST_ + 2*K0] = w;
      }
    }
    // MFMA chunk kc
    unsigned short* rp = (kc&1) ? apadB : apadA;
    uint2 u0 = *(const uint2*)&rp[row*AST_ + q*8];
    uint2 u1 = *(const uint2*)&rp[row*AST_ + q*8 + 4];
    uint4e ua = {u0.x, u0.y, u1.x, u1.y};
    short8 af = __builtin_bit_cast(short8, ua);
    #pragma unroll
    for (int dt = 0; dt < 8; dt++) {
      short8 bfg = *(const short8*)(wswz + (((size_t)kc*8 + dt)*64 + ln)*8);
      acc[dt] = __builtin_amdgcn_mfma_f32_16x16x32_bf16(af, bfg, acc[dt], 0, 0, 0);
    }
  }
  __syncthreads();   // all apad reads done before ytile alias writes

  #pragma unroll
  for (int dt = 0; dt < 8; dt++)
    #pragma unroll
    for (int r = 0; r < 4; r++)
      ytile[(wv*16 + q*4 + r)*136 + dt*16 + m] = f2bf(acc[dt][r]);
  __syncthreads();
  #pragma unroll
  for (int i = 0; i < 4; i++) {
    int idx = tid + i*256;
    int pp = idx >> 4, ch = idx & 15;
    uint4 v = *(const uint4*)&ytile[pp*136 + ch*8];
    *(uint4*)(val + ((size_t)bn*P_ + p0 + pp)*D_ + ch*8) = v;
  }
}

// ---------------------------------------------------------------------------
// attmlp (fused): one block owns 32 points. Phase A = attention+LN1
// (4 passes x 8 points, 32-lane group per point, 4 ch/lane, gathers issued
// in n-pairs ahead of math), writing bf16 z DIRECTLY into zt LDS — zbuf
// eliminated. Phase B = the mlp (MFMA bf16 GEMMs + GELU + residual + LN2),
// unchanged. XCD-chunked blockIdx swizzle (240%8==0 -> bijective) for val
// L2 locality during the gather phase.
// ---------------------------------------------------------------------------
__global__ __launch_bounds__(256, 4) void attmlp_kernel(
    const unsigned short* __restrict__ val, const float2* __restrict__ uvbuf,
    const float* __restrict__ ln1_g, const float* __restrict__ ln1_b,
    const unsigned short* __restrict__ w1s, const float* __restrict__ b1,
    const unsigned short* __restrict__ w2s, const float* __restrict__ b2,
    const float* __restrict__ ln2_g, const float* __restrict__ ln2_b,
    float* __restrict__ out) {
  __shared__ __align__(16) char smem[26112];
  unsigned short* zt = (unsigned short*)smem;            // 32*136*2 = 8704 B
  unsigned short* ht = (unsigned short*)(smem + 8704);   // 32*264*2 = 16896 B
  float* lnp = (float*)(smem + 25600);                   // [2][32][2] fp32 = 512 B
  float* yt = (float*)smem;                              // 128*34*4 = 17408 B (alias)

  int tid = threadIdx.x;
  int b = blockIdx.y;
  int bx = blockIdx.x;
  int tile = (bx & 7) * 30 + (bx >> 3);   // 240 tiles, 240%8==0 -> bijective
  int p0 = tile * 32;
  int ln = tid & 63, wv = tid >> 6;

  // ================= Phase A: attention + LN1 -> zt =================
  {
    int grp = ln >> 5, c = ln & 31;        // 2 points per wave, 32 lanes each
    float g1[4], be1[4];
    *(float4*)&g1[0]  = *(const float4*)(ln1_g + c*4);
    *(float4*)&be1[0] = *(const float4*)(ln1_b + c*4);

    for (int pass = 0; pass < 4; pass++) {
      int pl = pass*8 + wv*2 + grp;        // 0..31 local point
      int p = p0 + pl;

      uint2 qu = *(const uint2*)(val + ((size_t)(b*N_)*P_ + p)*D_ + c*4);
      float qv[4];
      bfu2(qu.x, qv[0], qv[1]); bfu2(qu.y, qv[2], qv[3]);
      float qp = 0.f;
      #pragma unroll
      for (int i = 0; i < 4; i++) qp += qv[i]*qv[i];
      float qinv = 1.f / fmaxf(sqrtf(gred32(qp)), 1e-12f);

      float dotv[N_];
      float sv[N_][4];
      #pragma unroll
      for (int np = 0; np < 3; np++) {
        uint2 g[2][4]; float wm[2][4]; bool vld[2];
        // issue phase: 8 gathers for two views
        #pragma unroll
        for (int t = 0; t < 2; t++) {
          int n = np*2 + t;
          float2 uv = uvbuf[((size_t)(b*N_ + n))*P_ + p];
          float sx = uv.x, sy = uv.y;
          float x0f = floorf(sx), y0f = floorf(sy);
          float fx = sx - x0f, fy = sy - y0f;
          int x0 = (int)x0f, y0 = (int)y0f;
          const unsigned short* base = val + ((size_t)(b*N_+n)*P_)*D_ + c*4;
          #pragma unroll
          for (int k = 0; k < 4; k++) {
            int dx = k & 1, dy = k >> 1;
            int cx = x0 + dx, cy = y0 + dy;
            bool inb = (cx >= 0) && (cx <= WF_-1) && (cy >= 0) && (cy <= HF_-1);
            int icx = min(max(cx,0),WF_-1), icy = min(max(cy,0),HF_-1);
            wm[t][k] = inb ? (dx ? fx : 1.f-fx) * (dy ? fy : 1.f-fy) : 0.f;
            g[t][k] = *(const uint2*)(base + (size_t)(icy*WF_ + icx)*D_);
          }
          vld[t] = (sx >= 0.f) && (sx <= (float)(WF_-1)) && (sy >= 0.f) && (sy <= (float)(HF_-1));
        }
        // math phase
        #pragma unroll
        for (int t = 0; t < 2; t++) {
          int n = np*2 + t;
          float acc[4];
          #pragma unroll
          for (int i = 0; i < 4; i++) acc[i] = 0.f;
          #pragma unroll
          for (int k = 0; k < 4; k++) {
            float gg[4];
            bfu2(g[t][k].x, gg[0], gg[1]); bfu2(g[t][k].y, gg[2], gg[3]);
            float w = wm[t][k];
            #pragma unroll
            for (int i = 0; i < 4; i++) acc[i] += gg[i]*w;
          }
          float ssp = 0.f, qsp = 0.f;
          #pragma unroll
          for (int i = 0; i < 4; i++) { ssp += acc[i]*acc[i]; qsp += qv[i]*acc[i]; }
          float ss = gred32(ssp);
          float qs = gred32(qsp);
          float dn = qs * qinv / fmaxf(sqrtf(ss), 1e-12f);
          dotv[n] = vld[t] ? dn : 0.f;
          #pragma unroll
          for (int i = 0; i < 4; i++) sv[n][i] = acc[i];
        }
      }
      // softmax over n
      float mx = dotv[0];
      #pragma unroll
      for (int n = 1; n < N_; n++) mx = fmaxf(mx, dotv[n]);
      float e[N_]; float den = 0.f;
      #pragma unroll
      for (int n = 0; n < N_; n++) { e[n] = expf(dotv[n]-mx); den += e[n]; }
      float rden = 1.f/den;
      float z[4];
      #pragma unroll
      for (int i = 0; i < 4; i++) z[i] = qv[i];
      #pragma unroll
      for (int n = 0; n < N_; n++) {
        float a = e[n]*rden;
        #pragma unroll
        for (int i = 0; i < 4; i++) z[i] += a*sv[n][i];
      }
      // LN1
      float sp = 0.f;
      #pragma unroll
      for (int i = 0; i < 4; i++) sp += z[i];
      float mu = gred32(sp) * (1.f/128.f);
      float vp = 0.f;
      #pragma unroll
      for (int i = 0; i < 4; i++) { float d0 = z[i]-mu; vp += d0*d0; }
      float rs = rsqrtf(gred32(vp) * (1.f/128.f) + 1e-5f);
      unsigned int ow[2];
      #pragma unroll
      for (int i = 0; i < 2; i++) {
        float o0 = (z[2*i]-mu)*rs*g1[2*i] + be1[2*i];
        float o1 = (z[2*i+1]-mu)*rs*g1[2*i+1] + be1[2*i+1];
        ow[i] = (unsigned int)f2bf(o0) | ((unsigned int)f2bf(o1) << 16);
      }
      *(uint2*)&zt[pl*136 + c*4] = make_uint2(ow[0], ow[1]);
    }
  }
  __syncthreads();   // zt fully written

  // ================= Phase B: MLP + LN2 -> out =================
  int m = ln & 15, q = ln >> 4;
  int h = wv >> 1, ch2 = wv & 1;   // p-half, col-half

  // GEMM1: 16 p x 128 cols per wave (8 col tiles), K=128
  floatx4 a1[8];
  #pragma unroll
  for (int j = 0; j < 8; j++) a1[j] = (floatx4){0.f,0.f,0.f,0.f};
  #pragma unroll
  for (int kc = 0; kc < 4; kc++) {
    short8 af = *(const short8*)&zt[(h*16+m)*136 + kc*32 + q*8];
    #pragma unroll
    for (int j = 0; j < 8; j++) {
      int dt = ch2*8 + j;
      short8 bfg = *(const short8*)(w1s + (((size_t)kc*16 + dt)*64 + ln)*8);
      a1[j] = __builtin_amdgcn_mfma_f32_16x16x32_bf16(af, bfg, a1[j], 0, 0, 0);
    }
  }
  #pragma unroll
  for (int j = 0; j < 8; j++) {
    int dt = ch2*8 + j;
    float bb = b1[dt*16 + m];
    #pragma unroll
    for (int r = 0; r < 4; r++) {
      float x = a1[j][r] + bb;
      float hv = 0.5f*x*(1.f + erff(x*0.70710678118654752f));
      ht[(h*16 + q*4 + r)*264 + dt*16 + m] = f2bf(hv);
    }
  }
  __syncthreads();

  // GEMM2: 16 p x 64 cols per wave (4 col tiles), K=256
  floatx4 a2[4];
  #pragma unroll
  for (int j = 0; j < 4; j++) a2[j] = (floatx4){0.f,0.f,0.f,0.f};
  #pragma unroll
  for (int kc = 0; kc < 8; kc++) {
    short8 af = *(const short8*)&ht[(h*16+m)*264 + kc*32 + q*8];
    #pragma unroll
    for (int j = 0; j < 4; j++) {
      int dt = ch2*4 + j;
      short8 bfg = *(const short8*)(w2s + (((size_t)kc*8 + dt)*64 + ln)*8);
      a2[j] = __builtin_amdgcn_mfma_f32_16x16x32_bf16(af, bfg, a2[j], 0, 0, 0);
    }
  }
  // bias + residual
  float y[4][4];
  #pragma unroll
  for (int j = 0; j < 4; j++) {
    int dt = ch2*4 + j;
    float bb = b2[dt*16 + m];
    #pragma unroll
    for (int r = 0; r < 4; r++) {
      int pp = h*16 + q*4 + r;
      y[j][r] = a2[j][r] + bb + bf2f(zt[pp*136 + dt*16 + m]);
    }
  }
  // LN2 partials (each wave covers 64 of 128 cols)
  #pragma unroll
  for (int r = 0; r < 4; r++) {
    float sp = 0.f, sq = 0.f;
    #pragma unroll
    for (int j = 0; j < 4; j++) { sp += y[j][r]; sq += y[j][r]*y[j][r]; }
    sp = gred_sum(sp); sq = gred_sum(sq);
    if (m == 0) {
      int pl = h*16 + q*4 + r;
      lnp[(ch2*32 + pl)*2 + 0] = sp;
      lnp[(ch2*32 + pl)*2 + 1] = sq;
    }
  }
  __syncthreads();
  float mu_[4], rs_[4];
  #pragma unroll
  for (int r = 0; r < 4; r++) {
    int pl = h*16 + q*4 + r;
    float sum = lnp[pl*2]     + lnp[(32+pl)*2];
    float ssq = lnp[pl*2 + 1] + lnp[(32+pl)*2 + 1];
    float mu = sum * (1.f/128.f);
    float var = fmaxf(ssq * (1.f/128.f) - mu*mu, 0.f);
    mu_[r] = mu; rs_[r] = rsqrtf(var + 1e-5f);
  }
  float gg[4], be[4];
  #pragma unroll
  for (int j = 0; j < 4; j++) {
    int d = (ch2*4 + j)*16 + m;
    gg[j] = ln2_g[d]; be[j] = ln2_b[d];
  }
  #pragma unroll
  for (int j = 0; j < 4; j++)
    #pragma unroll
    for (int r = 0; r < 4; r++)
      y[j][r] = (y[j][r] - mu_[r])*rs_[r]*gg[j] + be[j];
  __syncthreads();   // zt/ht/lnp reads done before yt alias writes
  #pragma unroll
  for (int j = 0; j < 4; j++)
    #pragma unroll
    for (int r = 0; r < 4; r++)
      yt[((ch2*4 + j)*16 + m)*34 + h*16 + q*4 + r] = y[j][r];
  __syncthreads();

  // transposed write: out[b, d, p0..p0+31]
  #pragma unroll
  for (int i = 0; i < 8; i++) {
    int idx = tid + i*256;    // 2048 float2 units = 128 d x 16
    int d = idx >> 4, pu = idx & 15;
    *(float2*)(out + ((size_t)(b*D_ + d))*P_ + p0 + pu*2) = *(float2*)&yt[d*34 + pu*2];
  }
}

// ---------------------------------------------------------------------------
extern "C" void kernel_launch(void* const* d_in, const int* in_sizes, int n_in,
                              void* d_out, int out_size, void* d_ws, size_t ws_size,
                              hipStream_t stream) {
  (void)in_sizes; (void)n_in; (void)out_size; (void)ws_size;
  const float* feature   = (const float*)d_in[0];
  const float* I_src     = (const float*)d_in[1];
  const float* I_tar_inv = (const float*)d_in[2];
  const float* E         = (const float*)d_in[3];
  const float* dis       = (const float*)d_in[4];
  const float* norm_vec  = (const float*)d_in[5];
  const float* bn_gamma  = (const float*)d_in[6];
  const float* bn_beta   = (const float*)d_in[7];
  const float* bn_mean   = (const float*)d_in[8];
  const float* bn_var    = (const float*)d_in[9];
  const float* conv_w    = (const float*)d_in[10];
  const float* ln1_g     = (const float*)d_in[11];
  const float* ln1_b     = (const float*)d_in[12];
  const float* mlp_w1    = (const float*)d_in[13];
  const float* mlp_b1    = (const float*)d_in[14];
  const float* mlp_w2    = (const float*)d_in[15];
  const float* mlp_b2    = (const float*)d_in[16];
  const float* ln2_g     = (const float*)d_in[17];
  const float* ln2_b     = (const float*)d_in[18];
  float* out = (float*)d_out;

  char* ws = (char*)d_ws;
  unsigned short* wswz = (unsigned short*)(ws + 0);          // 64 KB
  unsigned short* w1s  = (unsigned short*)(ws + 65536);      // 64 KB
  unsigned short* w2s  = (unsigned short*)(ws + 131072);     // 64 KB
  float2* uvbuf        = (float2*)(ws + 196608);             // 1.47 MB
  unsigned short* val  = (unsigned short*)(ws + 1671168);    // bf16 (B,N,P,D) 47.2 MB

  hipLaunchKernelGGL(setup_kernel, dim3(1104), dim3(256), 0, stream,
                     I_src, I_tar_inv, E, dis, norm_vec,
                     conv_w, mlp_w1, mlp_w2,
                     uvbuf, wswz, w1s, w2s);
  hipLaunchKernelGGL(conv_kernel, dim3(120, 24), dim3(256), 0, stream,
                     feature, wswz, bn_gamma, bn_beta, bn_mean, bn_var, val);
  hipLaunchKernelGGL(attmlp_kernel, dim3(240, 4), dim3(256), 0, stream,
                     val, uvbuf, ln1_g, ln1_b,
                     w1s, mlp_b1, w2s, mlp_b2, ln2_g, ln2_b, out);
}

// Round 4
// 350.408 us; speedup vs baseline: 1.0548x; 1.0235x over previous
//
#include <hip/hip_runtime.h>
#include <hip/hip_bf16.h>
#include <math.h>

#define B_ 4
#define N_ 6
#define FD_ 256
#define D_ 128
#define HF_ 64
#define WF_ 120
#define P_ (HF_*WF_)   // 7680

typedef __attribute__((ext_vector_type(8))) short short8;
typedef __attribute__((ext_vector_type(4))) float floatx4;
typedef __attribute__((ext_vector_type(4))) unsigned int uint4e;

__device__ inline float gred_sum(float v) {   // sum within 16-lane group
  v += __shfl_xor(v, 1); v += __shfl_xor(v, 2);
  v += __shfl_xor(v, 4); v += __shfl_xor(v, 8);
  return v;
}

__device__ inline float gred32(float v) {     // sum within 32-lane group
  v += __shfl_xor(v, 1); v += __shfl_xor(v, 2);
  v += __shfl_xor(v, 4); v += __shfl_xor(v, 8);
  v += __shfl_xor(v, 16);
  return v;
}

__device__ inline unsigned short f2bf(float f) {
  unsigned int u = __builtin_bit_cast(unsigned int, f);
  u += 0x7fffu + ((u >> 16) & 1u);   // RNE
  return (unsigned short)(u >> 16);
}
__device__ inline float bf2f(unsigned short h) {
  return __builtin_bit_cast(float, ((unsigned int)h) << 16);
}
__device__ inline void bfu2(unsigned int u, float& lo, float& hi) {
  lo = __builtin_bit_cast(float, u << 16);
  hi = __builtin_bit_cast(float, u & 0xffff0000u);
}

// HW packed f32x2 -> bf16x2 (RNE), single VALU op. gfx950-only; no builtin
// (learn_hip m240) so minimal non-volatile asm — scheduler can move it.
// Replaces the 7-8 op manual (f2bf | f2bf<<16) pair on conv's staging path.
__device__ inline unsigned int cvtpk_bf16(float lo, float hi) {
  unsigned int r;
  asm("v_cvt_pk_bf16_f32 %0, %1, %2" : "=v"(r) : "v"(lo), "v"(hi));
  return r;
}

// LDS-only barrier: orders LDS ops across the workgroup WITHOUT draining
// outstanding global loads (vmcnt). R1 A/B vs __syncthreads: neutral
// (TLP at 8 blocks/CU already hides the drain) — kept, harmless.
__device__ inline void lds_barrier() {
  asm volatile("s_waitcnt lgkmcnt(0)\n\ts_barrier" ::: "memory");
}

// ---------------------------------------------------------------------------
// setup: one kernel for uv precompute (homography computed per-thread,
// identical fp32 arithmetic to the old prep kernel) + conv_w swizzle +
// mlp weight swizzles. 1104 blocks = 720 uv + 128 swz_w + 256 swz_mlp.
// ---------------------------------------------------------------------------
__global__ __launch_bounds__(256) void setup_kernel(
    const float* __restrict__ I_src, const float* __restrict__ I_tar_inv,
    const float* __restrict__ E, const float* __restrict__ dis,
    const float* __restrict__ norm_vec,
    const float* __restrict__ conv_w, const float* __restrict__ w1,
    const float* __restrict__ w2,
    float2* __restrict__ uvbuf, unsigned short* __restrict__ wswz,
    unsigned short* __restrict__ w1s, unsigned short* __restrict__ w2s) {
  int bx = blockIdx.x;
  int tid = threadIdx.x;
  if (bx < 720) {
    // ---- uv part ----
    int t = bx*256 + tid;
    int p  = t % P_;
    int bn = t / P_;
    int b  = bn / N_;
    // homography (identical arithmetic to old prep_kernel)
    const float* e  = E + bn*16;
    const float* nv = norm_vec + b*3;
    float inv_dis = 1.0f / dis[0];
    float M[9];
    #pragma unroll
    for (int r = 0; r < 3; r++)
      #pragma unroll
      for (int c = 0; c < 3; c++)
        M[r*3+c] = e[r*4+c] - e[r*4+3]*nv[c]*inv_dis;
    const float* Is = I_src + bn*9;
    float A[9];
    #pragma unroll
    for (int r = 0; r < 3; r++)
      #pragma unroll
      for (int c = 0; c < 3; c++)
        A[r*3+c] = Is[r*3+0]*M[0*3+c] + Is[r*3+1]*M[1*3+c] + Is[r*3+2]*M[2*3+c];
    const float* It = I_tar_inv + b*9;
    float H[9];
    #pragma unroll
    for (int r = 0; r < 3; r++)
      #pragma unroll
      for (int c = 0; c < 3; c++)
        H[r*3+c] = A[r*3+0]*It[0*3+c] + A[r*3+1]*It[1*3+c] + A[r*3+2]*It[2*3+c];
    int py = p / WF_, px = p - py*WF_;
    float pixx = (float)px * (960.f/119.f);
    float pixy = (float)py * (480.f/63.f);
    float hx = H[0]*pixx + H[1]*pixy + H[2];
    float hy = H[3]*pixx + H[4]*pixy + H[5];
    float hz = H[6]*pixx + H[7]*pixy + H[8];
    float sx = (hx/hz) * ((float)WF_/960.f);
    float sy = (hy/hz) * ((float)HF_/480.f);
    uvbuf[t] = make_float2(sx, sy);
  } else if (bx < 848) {
    // ---- conv_w swizzle ----
    int t = (bx-720)*256 + tid;   // 0..32767
    int j    =  t        & 7;
    int lane = (t >> 3)  & 63;
    int dt   = (t >> 9)  & 7;
    int kc   =  t >> 12;
    int d = dt*16 + (lane & 15);
    int k = kc*32 + (lane >> 4)*8 + j;
    wswz[t] = f2bf(conv_w[d*FD_ + k]);
  } else {
    // ---- mlp weight swizzles ----
    int t = (bx-848)*256 + tid;   // 0..65535
    if (t < 32768) {
      int j    =  t        & 7;
      int lane = (t >> 3)  & 63;
      int dt   = (t >> 9)  & 15;
      int kc   =  t >> 13;
      int n = dt*16 + (lane & 15);
      int k = kc*32 + (lane >> 4)*8 + j;
      w1s[t] = f2bf(w1[k*256 + n]);
    } else {
      int u = t - 32768;
      int j    =  u        & 7;
      int lane = (u >> 3)  & 63;
      int dt   = (u >> 9)  & 7;
      int kc   =  u >> 12;
      int n = dt*16 + (lane & 15);
      int k = kc*32 + (lane >> 4)*8 + j;
      w2s[u] = f2bf(w2[k*128 + n]);
    }
  }
}

// ---------------------------------------------------------------------------
// conv (MFMA): depth-2 register prefetch, LDS-only in-loop barriers,
// LDS double-buffer, ytile aliases apad (19.4 KB LDS -> 8 blocks/CU).
// BN fold inline. Staging pack uses v_cvt_pk_bf16_f32 (1 op for the bf16
// pair vs ~8 manual ops) — conv is pack-VALU-bound (~33 us of f2bf at the
// VALU ceiling vs 37 us BW floor). block: 64 p x 128 d, 4 waves.
// ---------------------------------------------------------------------------
#define AST_ 36   // apad stride in shorts (72 B rows, 8B-aligned frag reads)
__global__ __launch_bounds__(256) void conv_kernel(const float* __restrict__ feature,
    const unsigned short* __restrict__ wswz,
    const float* __restrict__ bn_gamma, const float* __restrict__ bn_beta,
    const float* __restrict__ bn_mean, const float* __restrict__ bn_var,
    unsigned short* __restrict__ val) {
  __shared__ __align__(16) char csm[19968];
  unsigned short* apadA = (unsigned short*)csm;            // 64*36*2 = 4608 B
  unsigned short* apadB = (unsigned short*)(csm + 4608);   // 4608 B
  unsigned short* ytile = (unsigned short*)csm;            // 64*136*2 = 17408 B (alias)
  float* sbn = (float*)(csm + 17408);                      // 2048 B

  int tid = threadIdx.x;
  {
    float s = bn_gamma[tid] * rsqrtf(bn_var[tid] + 1e-5f);
    sbn[tid] = s;
    sbn[256+tid] = bn_beta[tid] - bn_mean[tid] * s;
  }

  int bn = blockIdx.y;
  int p0 = blockIdx.x * 64;
  const float* fbase2 = feature + (size_t)bn*FD_*P_ + p0;

  int K0 = tid >> 4;   // k-pair index within chunk
  int sp = (tid & 15) * 4;

  int ln = tid & 63, wv = tid >> 6;
  int m = ln & 15, q = ln >> 4;
  int row = wv*16 + m;

  float4 va[2], vb[2];
  // prolog loads: chunks 0,1
  {
    const float* fb0 = fbase2 + (size_t)(2*K0)*P_ + sp;
    va[0] = *(const float4*)fb0; vb[0] = *(const float4*)(fb0 + P_);
    const float* fb1 = fbase2 + (size_t)(32 + 2*K0)*P_ + sp;
    va[1] = *(const float4*)fb1; vb[1] = *(const float4*)(fb1 + P_);
  }
  __syncthreads();   // sbn visible

  floatx4 acc[8];
  #pragma unroll
  for (int dt = 0; dt < 8; dt++) acc[dt] = (floatx4){0.f,0.f,0.f,0.f};

  // pack chunk0 -> apadA
  {
    int k0 = 0;
    float s0 = sbn[k0+2*K0],   b0 = sbn[256+k0+2*K0];
    float s1 = sbn[k0+2*K0+1], b1 = sbn[256+k0+2*K0+1];
    float a0[4] = {va[0].x, va[0].y, va[0].z, va[0].w};
    float a1[4] = {vb[0].x, vb[0].y, vb[0].z, vb[0].w};
    #pragma unroll
    for (int i = 0; i < 4; i++) {
      unsigned int w = cvtpk_bf16(fmaxf(a0[i]*s0+b0, 0.f),
                                  fmaxf(a1[i]*s1+b1, 0.f));
      *(unsigned int*)&apadA[(sp+i)*AST_ + 2*K0] = w;
    }
  }

  #pragma unroll
  for (int kc = 0; kc < 8; kc++) {
    lds_barrier();   // LDS-only: does NOT drain the in-flight global loads
    // issue loads for chunk kc+2 (stay in flight across this whole iteration)
    if (kc + 2 < 8) {
      const float* fb = fbase2 + (size_t)((kc+2)*32 + 2*K0)*P_ + sp;
      va[kc&1] = *(const float4*)fb;
      vb[kc&1] = *(const float4*)(fb + P_);
    }
    // pack+write chunk kc+1 (its loads were issued a full iteration ago)
    if (kc + 1 < 8) {
      int s = (kc+1)&1;
      int k0 = (kc+1)*32;
      unsigned short* ap = ((kc+1)&1) ? apadB : apadA;
      float s0 = sbn[k0+2*K0],   b0 = sbn[256+k0+2*K0];
      float s1 = sbn[k0+2*K0+1], b1 = sbn[256+k0+2*K0+1];
      float a0[4] = {va[s].x, va[s].y, va[s].z, va[s].w};
      float a1[4] = {vb[s].x, vb[s].y, vb[s].z, vb[s].w};
      #pragma unroll
      for (int i = 0; i < 4; i++) {
        unsigned int w = cvtpk_bf16(fmaxf(a0[i]*s0+b0, 0.f),
                                    fmaxf(a1[i]*s1+b1, 0.f));
        *(unsigned int*)&ap[(sp+i)*AST_ + 2*K0] = w;
      }
    }
    // MFMA chunk kc
    unsigned short* rp = (kc&1) ? apadB : apadA;
    uint2 u0 = *(const uint2*)&rp[row*AST_ + q*8];
    uint2 u1 = *(const uint2*)&rp[row*AST_ + q*8 + 4];
    uint4e ua = {u0.x, u0.y, u1.x, u1.y};
    short8 af = __builtin_bit_cast(short8, ua);
    #pragma unroll
    for (int dt = 0; dt < 8; dt++) {
      short8 bfg = *(const short8*)(wswz + (((size_t)kc*8 + dt)*64 + ln)*8);
      acc[dt] = __builtin_amdgcn_mfma_f32_16x16x32_bf16(af, bfg, acc[dt], 0, 0, 0);
    }
  }
  __syncthreads();   // all apad reads done before ytile alias writes

  #pragma unroll
  for (int dt = 0; dt < 8; dt++)
    #pragma unroll
    for (int r = 0; r < 4; r++)
      ytile[(wv*16 + q*4 + r)*136 + dt*16 + m] = f2bf(acc[dt][r]);
  __syncthreads();
  #pragma unroll
  for (int i = 0; i < 4; i++) {
    int idx = tid + i*256;
    int pp = idx >> 4, ch = idx & 15;
    uint4 v = *(const uint4*)&ytile[pp*136 + ch*8];
    *(uint4*)(val + ((size_t)bn*P_ + p0 + pp)*D_ + ch*8) = v;
  }
}

// ---------------------------------------------------------------------------
// attmlp (fused): one block owns 32 points. Phase A = attention+LN1
// (4 passes x 8 points, 32-lane group per point, 4 ch/lane, gathers issued
// in n-pairs ahead of math), writing bf16 z DIRECTLY into zt LDS — zbuf
// eliminated. Phase B = the mlp (MFMA bf16 GEMMs + GELU + residual + LN2),
// unchanged. XCD-chunked blockIdx swizzle (240%8==0 -> bijective) for val
// L2 locality during the gather phase.
// ---------------------------------------------------------------------------
__global__ __launch_bounds__(256, 4) void attmlp_kernel(
    const unsigned short* __restrict__ val, const float2* __restrict__ uvbuf,
    const float* __restrict__ ln1_g, const float* __restrict__ ln1_b,
    const unsigned short* __restrict__ w1s, const float* __restrict__ b1,
    const unsigned short* __restrict__ w2s, const float* __restrict__ b2,
    const float* __restrict__ ln2_g, const float* __restrict__ ln2_b,
    float* __restrict__ out) {
  __shared__ __align__(16) char smem[26112];
  unsigned short* zt = (unsigned short*)smem;            // 32*136*2 = 8704 B
  unsigned short* ht = (unsigned short*)(smem + 8704);   // 32*264*2 = 16896 B
  float* lnp = (float*)(smem + 25600);                   // [2][32][2] fp32 = 512 B
  float* yt = (float*)smem;                              // 128*34*4 = 17408 B (alias)

  int tid = threadIdx.x;
  int b = blockIdx.y;
  int bx = blockIdx.x;
  int tile = (bx & 7) * 30 + (bx >> 3);   // 240 tiles, 240%8==0 -> bijective
  int p0 = tile * 32;
  int ln = tid & 63, wv = tid >> 6;

  // ================= Phase A: attention + LN1 -> zt =================
  {
    int grp = ln >> 5, c = ln & 31;        // 2 points per wave, 32 lanes each
    float g1[4], be1[4];
    *(float4*)&g1[0]  = *(const float4*)(ln1_g + c*4);
    *(float4*)&be1[0] = *(const float4*)(ln1_b + c*4);

    for (int pass = 0; pass < 4; pass++) {
      int pl = pass*8 + wv*2 + grp;        // 0..31 local point
      int p = p0 + pl;

      uint2 qu = *(const uint2*)(val + ((size_t)(b*N_)*P_ + p)*D_ + c*4);
      float qv[4];
      bfu2(qu.x, qv[0], qv[1]); bfu2(qu.y, qv[2], qv[3]);
      float qp = 0.f;
      #pragma unroll
      for (int i = 0; i < 4; i++) qp += qv[i]*qv[i];
      float qinv = 1.f / fmaxf(sqrtf(gred32(qp)), 1e-12f);

      float dotv[N_];
      float sv[N_][4];
      #pragma unroll
      for (int np = 0; np < 3; np++) {
        uint2 g[2][4]; float wm[2][4]; bool vld[2];
        // issue phase: 8 gathers for two views
        #pragma unroll
        for (int t = 0; t < 2; t++) {
          int n = np*2 + t;
          float2 uv = uvbuf[((size_t)(b*N_ + n))*P_ + p];
          float sx = uv.x, sy = uv.y;
          float x0f = floorf(sx), y0f = floorf(sy);
          float fx = sx - x0f, fy = sy - y0f;
          int x0 = (int)x0f, y0 = (int)y0f;
          const unsigned short* base = val + ((size_t)(b*N_+n)*P_)*D_ + c*4;
          #pragma unroll
          for (int k = 0; k < 4; k++) {
            int dx = k & 1, dy = k >> 1;
            int cx = x0 + dx, cy = y0 + dy;
            bool inb = (cx >= 0) && (cx <= WF_-1) && (cy >= 0) && (cy <= HF_-1);
            int icx = min(max(cx,0),WF_-1), icy = min(max(cy,0),HF_-1);
            wm[t][k] = inb ? (dx ? fx : 1.f-fx) * (dy ? fy : 1.f-fy) : 0.f;
            g[t][k] = *(const uint2*)(base + (size_t)(icy*WF_ + icx)*D_);
          }
          vld[t] = (sx >= 0.f) && (sx <= (float)(WF_-1)) && (sy >= 0.f) && (sy <= (float)(HF_-1));
        }
        // math phase
        #pragma unroll
        for (int t = 0; t < 2; t++) {
          int n = np*2 + t;
          float acc[4];
          #pragma unroll
          for (int i = 0; i < 4; i++) acc[i] = 0.f;
          #pragma unroll
          for (int k = 0; k < 4; k++) {
            float gg[4];
            bfu2(g[t][k].x, gg[0], gg[1]); bfu2(g[t][k].y, gg[2], gg[3]);
            float w = wm[t][k];
            #pragma unroll
            for (int i = 0; i < 4; i++) acc[i] += gg[i]*w;
          }
          float ssp = 0.f, qsp = 0.f;
          #pragma unroll
          for (int i = 0; i < 4; i++) { ssp += acc[i]*acc[i]; qsp += qv[i]*acc[i]; }
          float ss = gred32(ssp);
          float qs = gred32(qsp);
          float dn = qs * qinv / fmaxf(sqrtf(ss), 1e-12f);
          dotv[n] = vld[t] ? dn : 0.f;
          #pragma unroll
          for (int i = 0; i < 4; i++) sv[n][i] = acc[i];
        }
      }
      // softmax over n
      float mx = dotv[0];
      #pragma unroll
      for (int n = 1; n < N_; n++) mx = fmaxf(mx, dotv[n]);
      float e[N_]; float den = 0.f;
      #pragma unroll
      for (int n = 0; n < N_; n++) { e[n] = expf(dotv[n]-mx); den += e[n]; }
      float rden = 1.f/den;
      float z[4];
      #pragma unroll
      for (int i = 0; i < 4; i++) z[i] = qv[i];
      #pragma unroll
      for (int n = 0; n < N_; n++) {
        float a = e[n]*rden;
        #pragma unroll
        for (int i = 0; i < 4; i++) z[i] += a*sv[n][i];
      }
      // LN1
      float sp = 0.f;
      #pragma unroll
      for (int i = 0; i < 4; i++) sp += z[i];
      float mu = gred32(sp) * (1.f/128.f);
      float vp = 0.f;
      #pragma unroll
      for (int i = 0; i < 4; i++) { float d0 = z[i]-mu; vp += d0*d0; }
      float rs = rsqrtf(gred32(vp) * (1.f/128.f) + 1e-5f);
      unsigned int ow[2];
      #pragma unroll
      for (int i = 0; i < 2; i++) {
        float o0 = (z[2*i]-mu)*rs*g1[2*i] + be1[2*i];
        float o1 = (z[2*i+1]-mu)*rs*g1[2*i+1] + be1[2*i+1];
        ow[i] = (unsigned int)f2bf(o0) | ((unsigned int)f2bf(o1) << 16);
      }
      *(uint2*)&zt[pl*136 + c*4] = make_uint2(ow[0], ow[1]);
    }
  }
  __syncthreads();   // zt fully written

  // ================= Phase B: MLP + LN2 -> out =================
  int m = ln & 15, q = ln >> 4;
  int h = wv >> 1, ch2 = wv & 1;   // p-half, col-half

  // GEMM1: 16 p x 128 cols per wave (8 col tiles), K=128
  floatx4 a1[8];
  #pragma unroll
  for (int j = 0; j < 8; j++) a1[j] = (floatx4){0.f,0.f,0.f,0.f};
  #pragma unroll
  for (int kc = 0; kc < 4; kc++) {
    short8 af = *(const short8*)&zt[(h*16+m)*136 + kc*32 + q*8];
    #pragma unroll
    for (int j = 0; j < 8; j++) {
      int dt = ch2*8 + j;
      short8 bfg = *(const short8*)(w1s + (((size_t)kc*16 + dt)*64 + ln)*8);
      a1[j] = __builtin_amdgcn_mfma_f32_16x16x32_bf16(af, bfg, a1[j], 0, 0, 0);
    }
  }
  #pragma unroll
  for (int j = 0; j < 8; j++) {
    int dt = ch2*8 + j;
    float bb = b1[dt*16 + m];
    #pragma unroll
    for (int r = 0; r < 4; r++) {
      float x = a1[j][r] + bb;
      float hv = 0.5f*x*(1.f + erff(x*0.70710678118654752f));
      ht[(h*16 + q*4 + r)*264 + dt*16 + m] = f2bf(hv);
    }
  }
  __syncthreads();

  // GEMM2: 16 p x 64 cols per wave (4 col tiles), K=256
  floatx4 a2[4];
  #pragma unroll
  for (int j = 0; j < 4; j++) a2[j] = (floatx4){0.f,0.f,0.f,0.f};
  #pragma unroll
  for (int kc = 0; kc < 8; kc++) {
    short8 af = *(const short8*)&ht[(h*16+m)*264 + kc*32 + q*8];
    #pragma unroll
    for (int j = 0; j < 4; j++) {
      int dt = ch2*4 + j;
      short8 bfg = *(const short8*)(w2s + (((size_t)kc*8 + dt)*64 + ln)*8);
      a2[j] = __builtin_amdgcn_mfma_f32_16x16x32_bf16(af, bfg, a2[j], 0, 0, 0);
    }
  }
  // bias + residual
  float y[4][4];
  #pragma unroll
  for (int j = 0; j < 4; j++) {
    int dt = ch2*4 + j;
    float bb = b2[dt*16 + m];
    #pragma unroll
    for (int r = 0; r < 4; r++) {
      int pp = h*16 + q*4 + r;
      y[j][r] = a2[j][r] + bb + bf2f(zt[pp*136 + dt*16 + m]);
    }
  }
  // LN2 partials (each wave covers 64 of 128 cols)
  #pragma unroll
  for (int r = 0; r < 4; r++) {
    float sp = 0.f, sq = 0.f;
    #pragma unroll
    for (int j = 0; j < 4; j++) { sp += y[j][r]; sq += y[j][r]*y[j][r]; }
    sp = gred_sum(sp); sq = gred_sum(sq);
    if (m == 0) {
      int pl = h*16 + q*4 + r;
      lnp[(ch2*32 + pl)*2 + 0] = sp;
      lnp[(ch2*32 + pl)*2 + 1] = sq;
    }
  }
  __syncthreads();
  float mu_[4], rs_[4];
  #pragma unroll
  for (int r = 0; r < 4; r++) {
    int pl = h*16 + q*4 + r;
    float sum = lnp[pl*2]     + lnp[(32+pl)*2];
    float ssq = lnp[pl*2 + 1] + lnp[(32+pl)*2 + 1];
    float mu = sum * (1.f/128.f);
    float var = fmaxf(ssq * (1.f/128.f) - mu*mu, 0.f);
    mu_[r] = mu; rs_[r] = rsqrtf(var + 1e-5f);
  }
  float gg[4], be[4];
  #pragma unroll
  for (int j = 0; j < 4; j++) {
    int d = (ch2*4 + j)*16 + m;
    gg[j] = ln2_g[d]; be[j] = ln2_b[d];
  }
  #pragma unroll
  for (int j = 0; j < 4; j++)
    #pragma unroll
    for (int r = 0; r < 4; r++)
      y[j][r] = (y[j][r] - mu_[r])*rs_[r]*gg[j] + be[j];
  __syncthreads();   // zt/ht/lnp reads done before yt alias writes
  #pragma unroll
  for (int j = 0; j < 4; j++)
    #pragma unroll
    for (int r = 0; r < 4; r++)
      yt[((ch2*4 + j)*16 + m)*34 + h*16 + q*4 + r] = y[j][r];
  __syncthreads();

  // transposed write: out[b, d, p0..p0+31]
  #pragma unroll
  for (int i = 0; i < 8; i++) {
    int idx = tid + i*256;    // 2048 float2 units = 128 d x 16
    int d = idx >> 4, pu = idx & 15;
    *(float2*)(out + ((size_t)(b*D_ + d))*P_ + p0 + pu*2) = *(float2*)&yt[d*34 + pu*2];
  }
}

// ---------------------------------------------------------------------------
extern "C" void kernel_launch(void* const* d_in, const int* in_sizes, int n_in,
                              void* d_out, int out_size, void* d_ws, size_t ws_size,
                              hipStream_t stream) {
  (void)in_sizes; (void)n_in; (void)out_size; (void)ws_size;
  const float* feature   = (const float*)d_in[0];
  const float* I_src     = (const float*)d_in[1];
  const float* I_tar_inv = (const float*)d_in[2];
  const float* E         = (const float*)d_in[3];
  const float* dis       = (const float*)d_in[4];
  const float* norm_vec  = (const float*)d_in[5];
  const float* bn_gamma  = (const float*)d_in[6];
  const float* bn_beta   = (const float*)d_in[7];
  const float* bn_mean   = (const float*)d_in[8];
  const float* bn_var    = (const float*)d_in[9];
  const float* conv_w    = (const float*)d_in[10];
  const float* ln1_g     = (const float*)d_in[11];
  const float* ln1_b     = (const float*)d_in[12];
  const float* mlp_w1    = (const float*)d_in[13];
  const float* mlp_b1    = (const float*)d_in[14];
  const float* mlp_w2    = (const float*)d_in[15];
  const float* mlp_b2    = (const float*)d_in[16];
  const float* ln2_g     = (const float*)d_in[17];
  const float* ln2_b     = (const float*)d_in[18];
  float* out = (float*)d_out;

  char* ws = (char*)d_ws;
  unsigned short* wswz = (unsigned short*)(ws + 0);          // 64 KB
  unsigned short* w1s  = (unsigned short*)(ws + 65536);      // 64 KB
  unsigned short* w2s  = (unsigned short*)(ws + 131072);     // 64 KB
  float2* uvbuf        = (float2*)(ws + 196608);             // 1.47 MB
  unsigned short* val  = (unsigned short*)(ws + 1671168);    // bf16 (B,N,P,D) 47.2 MB

  hipLaunchKernelGGL(setup_kernel, dim3(1104), dim3(256), 0, stream,
                     I_src, I_tar_inv, E, dis, norm_vec,
                     conv_w, mlp_w1, mlp_w2,
                     uvbuf, wswz, w1s, w2s);
  hipLaunchKernelGGL(conv_kernel, dim3(120, 24), dim3(256), 0, stream,
                     feature, wswz, bn_gamma, bn_beta, bn_mean, bn_var, val);
  hipLaunchKernelGGL(attmlp_kernel, dim3(240, 4), dim3(256), 0, stream,
                     val, uvbuf, ln1_g, ln1_b,
                     w1s, mlp_b1, w2s, mlp_b2, ln2_g, ln2_b, out);
}